// Round 1
// baseline (6532.984 us; speedup 1.0000x reference)
//
#include <hip/hip_runtime.h>
#include <math.h>

#define NN 100000
#define EE 400000
#define DD 128
#define HH 4

__device__ __forceinline__ void atomicMaxFloat(float* addr, float val) {
  if (val >= 0.0f) {
    atomicMax((int*)addr, __float_as_int(val));
  } else {
    atomicMin((unsigned int*)addr, __float_as_uint(val));
  }
}

// C[M x 128] = A[M x 128] @ W[128 x 128] (+ bias)
// block = 256 threads = 4 waves; wave ty owns 32 columns (wave-uniform LDS reads
// -> broadcast, conflict-free); lane tx owns one row of a 64-row tile.
__global__ __launch_bounds__(256) void gemm128(
    const float* __restrict__ A, const float* __restrict__ W,
    const float* __restrict__ bias, float* __restrict__ C, int M) {
  __shared__ float Wl[DD * DD];
  const int tid = threadIdx.x;
  {
    const float4* __restrict__ W4 = (const float4*)W;
    float4* Wl4 = (float4*)Wl;
#pragma unroll
    for (int i = 0; i < 16; ++i) Wl4[tid + i * 256] = W4[tid + i * 256];
  }
  __syncthreads();
  const int tx = tid & 63, ty = tid >> 6;
  const int r = blockIdx.x * 64 + tx;
  if (r >= M) return;
  const float4* __restrict__ Arow = (const float4*)(A + (size_t)r * DD);
  const int c0 = ty * 32;
  float acc[32];
#pragma unroll
  for (int j = 0; j < 32; ++j) acc[j] = 0.0f;
  for (int k4 = 0; k4 < 32; ++k4) {
    const float4 a = Arow[k4];
    const float4* w0 = (const float4*)(Wl + (k4 * 4 + 0) * DD + c0);
    const float4* w1 = (const float4*)(Wl + (k4 * 4 + 1) * DD + c0);
    const float4* w2 = (const float4*)(Wl + (k4 * 4 + 2) * DD + c0);
    const float4* w3 = (const float4*)(Wl + (k4 * 4 + 3) * DD + c0);
#pragma unroll
    for (int j4 = 0; j4 < 8; ++j4) {
      float4 b;
      b = w0[j4];
      acc[4*j4+0] += a.x * b.x; acc[4*j4+1] += a.x * b.y;
      acc[4*j4+2] += a.x * b.z; acc[4*j4+3] += a.x * b.w;
      b = w1[j4];
      acc[4*j4+0] += a.y * b.x; acc[4*j4+1] += a.y * b.y;
      acc[4*j4+2] += a.y * b.z; acc[4*j4+3] += a.y * b.w;
      b = w2[j4];
      acc[4*j4+0] += a.z * b.x; acc[4*j4+1] += a.z * b.y;
      acc[4*j4+2] += a.z * b.z; acc[4*j4+3] += a.z * b.w;
      b = w3[j4];
      acc[4*j4+0] += a.w * b.x; acc[4*j4+1] += a.w * b.y;
      acc[4*j4+2] += a.w * b.z; acc[4*j4+3] += a.w * b.w;
    }
  }
  float4* Crow = (float4*)(C + (size_t)r * DD + c0);
  if (bias) {
    const float4* b4 = (const float4*)(bias + c0);
#pragma unroll
    for (int j4 = 0; j4 < 8; ++j4) {
      float4 bb = b4[j4];
      float4 o;
      o.x = acc[4*j4+0] + bb.x; o.y = acc[4*j4+1] + bb.y;
      o.z = acc[4*j4+2] + bb.z; o.w = acc[4*j4+3] + bb.w;
      Crow[j4] = o;
    }
  } else {
#pragma unroll
    for (int j4 = 0; j4 < 8; ++j4) {
      float4 o;
      o.x = acc[4*j4+0]; o.y = acc[4*j4+1];
      o.z = acc[4*j4+2]; o.w = acc[4*j4+3];
      Crow[j4] = o;
    }
  }
}

// out = relu(LN(h + agg@W + bu) * g + be), fused GEMM + LayerNorm.
// Reuses Wl's first 2KB for the cross-wave row reduction after the k-loop.
__global__ __launch_bounds__(256) void update_ln(
    const float* __restrict__ h, const float* __restrict__ agg,
    const float* __restrict__ W, const float* __restrict__ bu,
    const float* __restrict__ g, const float* __restrict__ be,
    float* __restrict__ out, int M) {
  __shared__ float Wl[DD * DD];
  const int tid = threadIdx.x;
  {
    const float4* __restrict__ W4 = (const float4*)W;
    float4* Wl4 = (float4*)Wl;
#pragma unroll
    for (int i = 0; i < 16; ++i) Wl4[tid + i * 256] = W4[tid + i * 256];
  }
  __syncthreads();
  const int tx = tid & 63, ty = tid >> 6;
  const int r = blockIdx.x * 64 + tx;
  const bool valid = (r < M);
  const int c0 = ty * 32;
  float acc[32];
#pragma unroll
  for (int j = 0; j < 32; ++j) acc[j] = 0.0f;
  if (valid) {
    const float4* __restrict__ Arow = (const float4*)(agg + (size_t)r * DD);
    for (int k4 = 0; k4 < 32; ++k4) {
      const float4 a = Arow[k4];
      const float4* w0 = (const float4*)(Wl + (k4 * 4 + 0) * DD + c0);
      const float4* w1 = (const float4*)(Wl + (k4 * 4 + 1) * DD + c0);
      const float4* w2 = (const float4*)(Wl + (k4 * 4 + 2) * DD + c0);
      const float4* w3 = (const float4*)(Wl + (k4 * 4 + 3) * DD + c0);
#pragma unroll
      for (int j4 = 0; j4 < 8; ++j4) {
        float4 b;
        b = w0[j4];
        acc[4*j4+0] += a.x * b.x; acc[4*j4+1] += a.x * b.y;
        acc[4*j4+2] += a.x * b.z; acc[4*j4+3] += a.x * b.w;
        b = w1[j4];
        acc[4*j4+0] += a.y * b.x; acc[4*j4+1] += a.y * b.y;
        acc[4*j4+2] += a.y * b.z; acc[4*j4+3] += a.y * b.w;
        b = w2[j4];
        acc[4*j4+0] += a.z * b.x; acc[4*j4+1] += a.z * b.y;
        acc[4*j4+2] += a.z * b.z; acc[4*j4+3] += a.z * b.w;
        b = w3[j4];
        acc[4*j4+0] += a.w * b.x; acc[4*j4+1] += a.w * b.y;
        acc[4*j4+2] += a.w * b.z; acc[4*j4+3] += a.w * b.w;
      }
    }
    // x = h + agg@W + bu
    const float4* hrow = (const float4*)(h + (size_t)r * DD + c0);
    const float4* bu4 = (const float4*)(bu + c0);
#pragma unroll
    for (int j4 = 0; j4 < 8; ++j4) {
      float4 hv = hrow[j4], bv = bu4[j4];
      acc[4*j4+0] += hv.x + bv.x; acc[4*j4+1] += hv.y + bv.y;
      acc[4*j4+2] += hv.z + bv.z; acc[4*j4+3] += hv.w + bv.w;
    }
  }
  float psum = 0.0f, psq = 0.0f;
  if (valid) {
#pragma unroll
    for (int j = 0; j < 32; ++j) { psum += acc[j]; psq += acc[j] * acc[j]; }
  }
  __syncthreads();  // all Wl reads done
  float* red = Wl;  // reuse LDS
  red[ty * 64 + tx] = psum;
  red[256 + ty * 64 + tx] = psq;
  __syncthreads();
  const float s0 = red[tx] + red[64 + tx] + red[128 + tx] + red[192 + tx];
  const float s1 = red[256 + tx] + red[320 + tx] + red[384 + tx] + red[448 + tx];
  const float mean = s0 * (1.0f / 128.0f);
  const float var = s1 * (1.0f / 128.0f) - mean * mean;
  const float inv = rsqrtf(var + 1e-5f);
  if (valid) {
    float4* orow = (float4*)(out + (size_t)r * DD + c0);
    const float4* g4 = (const float4*)(g + c0);
    const float4* be4 = (const float4*)(be + c0);
#pragma unroll
    for (int j4 = 0; j4 < 8; ++j4) {
      float4 gv = g4[j4], bv = be4[j4];
      float4 o;
      o.x = fmaxf((acc[4*j4+0] - mean) * inv * gv.x + bv.x, 0.0f);
      o.y = fmaxf((acc[4*j4+1] - mean) * inv * gv.y + bv.y, 0.0f);
      o.z = fmaxf((acc[4*j4+2] - mean) * inv * gv.z + bv.z, 0.0f);
      o.w = fmaxf((acc[4*j4+3] - mean) * inv * gv.w + bv.w, 0.0f);
      orow[j4] = o;
    }
  }
}

__global__ void init_rel(float* __restrict__ m, float* __restrict__ ssum,
                         float* __restrict__ agg) {
  const int i = blockIdx.x * 256 + threadIdx.x;
  if (i < NN * HH) { m[i] = -INFINITY; ssum[i] = 0.0f; }
  if (i < NN * DD) agg[i] = 0.0f;
}

// per-edge: scores[e][h] = <Q[dst], K[src]>_head / sqrt(32); atomic max into m
__global__ void scores_kernel(const float* __restrict__ Hq, const float* __restrict__ K,
                              const int* __restrict__ src, const int* __restrict__ dst,
                              float* __restrict__ s, float* __restrict__ m) {
  const int e = blockIdx.x * 256 + threadIdx.x;
  if (e >= EE) return;
  const int sd = src[e], dd = dst[e];
  const float4* __restrict__ q = (const float4*)(Hq + (size_t)dd * DD);
  const float4* __restrict__ kk = (const float4*)(K + (size_t)sd * DD);
  float sc[4] = {0.0f, 0.0f, 0.0f, 0.0f};
#pragma unroll 8
  for (int i = 0; i < 32; ++i) {
    const float4 a = q[i], b = kk[i];
    sc[i >> 3] += a.x * b.x + a.y * b.y + a.z * b.z + a.w * b.w;
  }
  const float inv = 0.17677669529663689f;  // 1/sqrt(32)
#pragma unroll
  for (int hh = 0; hh < 4; ++hh) {
    const float v = sc[hh] * inv;
    s[(size_t)e * 4 + hh] = v;
    atomicMaxFloat(&m[(size_t)dd * 4 + hh], v);
  }
}

__global__ void expsum_kernel(float* __restrict__ s, const float* __restrict__ m,
                              float* __restrict__ ssum, const int* __restrict__ dst) {
  const int e = blockIdx.x * 256 + threadIdx.x;
  if (e >= EE) return;
  const int dd = dst[e];
  float4 sv = ((const float4*)s)[e];
  const float4 mv = ((const float4*)m)[dd];
  sv.x = expf(sv.x - mv.x);
  sv.y = expf(sv.y - mv.y);
  sv.z = expf(sv.z - mv.z);
  sv.w = expf(sv.w - mv.w);
  ((float4*)s)[e] = sv;
  atomicAdd(&ssum[dd * 4 + 0], sv.x);
  atomicAdd(&ssum[dd * 4 + 1], sv.y);
  atomicAdd(&ssum[dd * 4 + 2], sv.z);
  atomicAdd(&ssum[dd * 4 + 3], sv.w);
}

__global__ void scatter_kernel(const float* __restrict__ s, const float* __restrict__ ssum,
                               const float* __restrict__ V, const int* __restrict__ src,
                               const int* __restrict__ dst, float* __restrict__ agg) {
  const int e = blockIdx.x * 256 + threadIdx.x;
  if (e >= EE) return;
  const int sd = src[e], dd = dst[e];
  const float4 ex = ((const float4*)s)[e];
  const float4 sm = ((const float4*)ssum)[dd];
  float at[4] = {ex.x / sm.x, ex.y / sm.y, ex.z / sm.z, ex.w / sm.w};
  const float4* __restrict__ v = (const float4*)(V + (size_t)sd * DD);
  float* arow = agg + (size_t)dd * DD;
#pragma unroll 8
  for (int i = 0; i < 32; ++i) {
    const float4 vv = v[i];
    const float a = at[i >> 3];
    atomicAdd(&arow[i * 4 + 0], vv.x * a);
    atomicAdd(&arow[i * 4 + 1], vv.y * a);
    atomicAdd(&arow[i * 4 + 2], vv.z * a);
    atomicAdd(&arow[i * 4 + 3], vv.w * a);
  }
}

extern "C" void kernel_launch(void* const* d_in, const int* in_sizes, int n_in,
                              void* d_out, int out_size, void* d_ws, size_t ws_size,
                              hipStream_t stream) {
  const float* x_drug  = (const float*)d_in[0];
  const float* x_dis   = (const float*)d_in[1];
  const float* Wp_drug = (const float*)d_in[2];
  const float* bp_drug = (const float*)d_in[3];
  const float* Wp_dis  = (const float*)d_in[4];
  const float* bp_dis  = (const float*)d_in[5];
  const float* Wk_r0   = (const float*)d_in[6];
  const float* Wv_r0   = (const float*)d_in[7];
  const float* Wk_r1   = (const float*)d_in[8];
  const float* Wv_r1   = (const float*)d_in[9];
  const float* Wu_drug = (const float*)d_in[10];
  const float* bu_drug = (const float*)d_in[11];
  const float* Wu_dis  = (const float*)d_in[12];
  const float* bu_dis  = (const float*)d_in[13];
  const float* g_drug  = (const float*)d_in[14];
  const float* be_drug = (const float*)d_in[15];
  const float* g_dis   = (const float*)d_in[16];
  const float* be_dis  = (const float*)d_in[17];
  const int* ei_r0     = (const int*)d_in[18];
  const int* ei_r1     = (const int*)d_in[19];

  float* out = (float*)d_out;
  float* h_drug = out;              // [N,D] — overwritten by update_ln at the end
  float* h_dis  = out + (size_t)NN * DD;

  const size_t ND = (size_t)NN * DD;
  float* ws     = (float*)d_ws;
  float* Kbuf   = ws;               // N*D
  float* Vbuf   = Kbuf + ND;        // N*D
  float* aggdr  = Vbuf + ND;        // N*D  (agg for drug, from r1)
  float* aggdi  = aggdr + ND;       // N*D  (agg for dis,  from r0)
  float* sbuf   = aggdi + ND;       // E*4
  float* mbuf   = sbuf + (size_t)EE * 4;  // N*4
  float* sumbuf = mbuf + (size_t)NN * 4;  // N*4

  const int gemm_blocks = (NN + 63) / 64;
  const int edge_blocks = (EE + 255) / 256;
  const int init_blocks = (NN * DD + 255) / 256;
  dim3 b256(256);

  // type-specific projection -> h lives in d_out for now
  gemm128<<<gemm_blocks, b256, 0, stream>>>(x_drug, Wp_drug, bp_drug, h_drug, NN);
  gemm128<<<gemm_blocks, b256, 0, stream>>>(x_dis,  Wp_dis,  bp_dis,  h_dis,  NN);

  // relation 0: drug -> dis   (K,V from h_drug; Q from h_dis)
  gemm128<<<gemm_blocks, b256, 0, stream>>>(h_drug, Wk_r0, nullptr, Kbuf, NN);
  gemm128<<<gemm_blocks, b256, 0, stream>>>(h_drug, Wv_r0, nullptr, Vbuf, NN);
  init_rel<<<init_blocks, b256, 0, stream>>>(mbuf, sumbuf, aggdi);
  scores_kernel<<<edge_blocks, b256, 0, stream>>>(h_dis, Kbuf, ei_r0, ei_r0 + EE, sbuf, mbuf);
  expsum_kernel<<<edge_blocks, b256, 0, stream>>>(sbuf, mbuf, sumbuf, ei_r0 + EE);
  scatter_kernel<<<edge_blocks, b256, 0, stream>>>(sbuf, sumbuf, Vbuf, ei_r0, ei_r0 + EE, aggdi);

  // relation 1: dis -> drug   (K,V from h_dis; Q from h_drug)
  gemm128<<<gemm_blocks, b256, 0, stream>>>(h_dis, Wk_r1, nullptr, Kbuf, NN);
  gemm128<<<gemm_blocks, b256, 0, stream>>>(h_dis, Wv_r1, nullptr, Vbuf, NN);
  init_rel<<<init_blocks, b256, 0, stream>>>(mbuf, sumbuf, aggdr);
  scores_kernel<<<edge_blocks, b256, 0, stream>>>(h_drug, Kbuf, ei_r1, ei_r1 + EE, sbuf, mbuf);
  expsum_kernel<<<edge_blocks, b256, 0, stream>>>(sbuf, mbuf, sumbuf, ei_r1 + EE);
  scatter_kernel<<<edge_blocks, b256, 0, stream>>>(sbuf, sumbuf, Vbuf, ei_r1, ei_r1 + EE, aggdr);

  // update + LayerNorm + ReLU (reads h from d_out, overwrites in place)
  update_ln<<<gemm_blocks, b256, 0, stream>>>(h_drug, aggdr, Wu_drug, bu_drug, g_drug, be_drug, h_drug, NN);
  update_ln<<<gemm_blocks, b256, 0, stream>>>(h_dis,  aggdi, Wu_dis,  bu_dis,  g_dis,  be_dis,  h_dis,  NN);
}

// Round 2
// 888.563 us; speedup vs baseline: 7.3523x; 7.3523x over previous
//
#include <hip/hip_runtime.h>
#include <math.h>

#define NN 100000
#define EE 400000
#define DD 128
#define HH 4

// ---------------- dense GEMM: C[M x 128] = A[M x 128] @ W[128 x 128] (+ bias)
__global__ __launch_bounds__(256) void gemm128(
    const float* __restrict__ A, const float* __restrict__ W,
    const float* __restrict__ bias, float* __restrict__ C, int M) {
  __shared__ float Wl[DD * DD];
  const int tid = threadIdx.x;
  {
    const float4* __restrict__ W4 = (const float4*)W;
    float4* Wl4 = (float4*)Wl;
#pragma unroll
    for (int i = 0; i < 16; ++i) Wl4[tid + i * 256] = W4[tid + i * 256];
  }
  __syncthreads();
  const int tx = tid & 63, ty = tid >> 6;
  const int r = blockIdx.x * 64 + tx;
  if (r >= M) return;
  const float4* __restrict__ Arow = (const float4*)(A + (size_t)r * DD);
  const int c0 = ty * 32;
  float acc[32];
#pragma unroll
  for (int j = 0; j < 32; ++j) acc[j] = 0.0f;
  for (int k4 = 0; k4 < 32; ++k4) {
    const float4 a = Arow[k4];
    const float4* w0 = (const float4*)(Wl + (k4 * 4 + 0) * DD + c0);
    const float4* w1 = (const float4*)(Wl + (k4 * 4 + 1) * DD + c0);
    const float4* w2 = (const float4*)(Wl + (k4 * 4 + 2) * DD + c0);
    const float4* w3 = (const float4*)(Wl + (k4 * 4 + 3) * DD + c0);
#pragma unroll
    for (int j4 = 0; j4 < 8; ++j4) {
      float4 b;
      b = w0[j4];
      acc[4*j4+0] += a.x * b.x; acc[4*j4+1] += a.x * b.y;
      acc[4*j4+2] += a.x * b.z; acc[4*j4+3] += a.x * b.w;
      b = w1[j4];
      acc[4*j4+0] += a.y * b.x; acc[4*j4+1] += a.y * b.y;
      acc[4*j4+2] += a.y * b.z; acc[4*j4+3] += a.y * b.w;
      b = w2[j4];
      acc[4*j4+0] += a.z * b.x; acc[4*j4+1] += a.z * b.y;
      acc[4*j4+2] += a.z * b.z; acc[4*j4+3] += a.z * b.w;
      b = w3[j4];
      acc[4*j4+0] += a.w * b.x; acc[4*j4+1] += a.w * b.y;
      acc[4*j4+2] += a.w * b.z; acc[4*j4+3] += a.w * b.w;
    }
  }
  float4* Crow = (float4*)(C + (size_t)r * DD + c0);
  if (bias) {
    const float4* b4 = (const float4*)(bias + c0);
#pragma unroll
    for (int j4 = 0; j4 < 8; ++j4) {
      float4 bb = b4[j4];
      float4 o;
      o.x = acc[4*j4+0] + bb.x; o.y = acc[4*j4+1] + bb.y;
      o.z = acc[4*j4+2] + bb.z; o.w = acc[4*j4+3] + bb.w;
      Crow[j4] = o;
    }
  } else {
#pragma unroll
    for (int j4 = 0; j4 < 8; ++j4) {
      float4 o;
      o.x = acc[4*j4+0]; o.y = acc[4*j4+1];
      o.z = acc[4*j4+2]; o.w = acc[4*j4+3];
      Crow[j4] = o;
    }
  }
}

// ---------------- fused update GEMM + LayerNorm + ReLU
__global__ __launch_bounds__(256) void update_ln(
    const float* __restrict__ h, const float* __restrict__ agg,
    const float* __restrict__ W, const float* __restrict__ bu,
    const float* __restrict__ g, const float* __restrict__ be,
    float* __restrict__ out, int M) {
  __shared__ float Wl[DD * DD];
  const int tid = threadIdx.x;
  {
    const float4* __restrict__ W4 = (const float4*)W;
    float4* Wl4 = (float4*)Wl;
#pragma unroll
    for (int i = 0; i < 16; ++i) Wl4[tid + i * 256] = W4[tid + i * 256];
  }
  __syncthreads();
  const int tx = tid & 63, ty = tid >> 6;
  const int r = blockIdx.x * 64 + tx;
  const bool valid = (r < M);
  const int c0 = ty * 32;
  float acc[32];
#pragma unroll
  for (int j = 0; j < 32; ++j) acc[j] = 0.0f;
  if (valid) {
    const float4* __restrict__ Arow = (const float4*)(agg + (size_t)r * DD);
    for (int k4 = 0; k4 < 32; ++k4) {
      const float4 a = Arow[k4];
      const float4* w0 = (const float4*)(Wl + (k4 * 4 + 0) * DD + c0);
      const float4* w1 = (const float4*)(Wl + (k4 * 4 + 1) * DD + c0);
      const float4* w2 = (const float4*)(Wl + (k4 * 4 + 2) * DD + c0);
      const float4* w3 = (const float4*)(Wl + (k4 * 4 + 3) * DD + c0);
#pragma unroll
      for (int j4 = 0; j4 < 8; ++j4) {
        float4 b;
        b = w0[j4];
        acc[4*j4+0] += a.x * b.x; acc[4*j4+1] += a.x * b.y;
        acc[4*j4+2] += a.x * b.z; acc[4*j4+3] += a.x * b.w;
        b = w1[j4];
        acc[4*j4+0] += a.y * b.x; acc[4*j4+1] += a.y * b.y;
        acc[4*j4+2] += a.y * b.z; acc[4*j4+3] += a.y * b.w;
        b = w2[j4];
        acc[4*j4+0] += a.z * b.x; acc[4*j4+1] += a.z * b.y;
        acc[4*j4+2] += a.z * b.z; acc[4*j4+3] += a.z * b.w;
        b = w3[j4];
        acc[4*j4+0] += a.w * b.x; acc[4*j4+1] += a.w * b.y;
        acc[4*j4+2] += a.w * b.z; acc[4*j4+3] += a.w * b.w;
      }
    }
    const float4* hrow = (const float4*)(h + (size_t)r * DD + c0);
    const float4* bu4 = (const float4*)(bu + c0);
#pragma unroll
    for (int j4 = 0; j4 < 8; ++j4) {
      float4 hv = hrow[j4], bv = bu4[j4];
      acc[4*j4+0] += hv.x + bv.x; acc[4*j4+1] += hv.y + bv.y;
      acc[4*j4+2] += hv.z + bv.z; acc[4*j4+3] += hv.w + bv.w;
    }
  }
  float psum = 0.0f, psq = 0.0f;
  if (valid) {
#pragma unroll
    for (int j = 0; j < 32; ++j) { psum += acc[j]; psq += acc[j] * acc[j]; }
  }
  __syncthreads();
  float* red = Wl;
  red[ty * 64 + tx] = psum;
  red[256 + ty * 64 + tx] = psq;
  __syncthreads();
  const float s0 = red[tx] + red[64 + tx] + red[128 + tx] + red[192 + tx];
  const float s1 = red[256 + tx] + red[320 + tx] + red[384 + tx] + red[448 + tx];
  const float mean = s0 * (1.0f / 128.0f);
  const float var = s1 * (1.0f / 128.0f) - mean * mean;
  const float inv = rsqrtf(var + 1e-5f);
  if (valid) {
    float4* orow = (float4*)(out + (size_t)r * DD + c0);
    const float4* g4 = (const float4*)(g + c0);
    const float4* be4 = (const float4*)(be + c0);
#pragma unroll
    for (int j4 = 0; j4 < 8; ++j4) {
      float4 gv = g4[j4], bv = be4[j4];
      float4 o;
      o.x = fmaxf((acc[4*j4+0] - mean) * inv * gv.x + bv.x, 0.0f);
      o.y = fmaxf((acc[4*j4+1] - mean) * inv * gv.y + bv.y, 0.0f);
      o.z = fmaxf((acc[4*j4+2] - mean) * inv * gv.z + bv.z, 0.0f);
      o.w = fmaxf((acc[4*j4+3] - mean) * inv * gv.w + bv.w, 0.0f);
      orow[j4] = o;
    }
  }
}

// ---------------- CSR build ----------------
__global__ __launch_bounds__(256) void count_deg(const int* __restrict__ dst,
                                                 int* __restrict__ deg) {
  const int e = blockIdx.x * 256 + threadIdx.x;
  if (e < EE) atomicAdd(&deg[dst[e]], 1);
}

// exclusive scan stage 1: per-1024-chunk scan + chunk totals
__global__ __launch_bounds__(256) void scan1(const int* __restrict__ deg,
                                             int* __restrict__ excl,
                                             int* __restrict__ partials, int n) {
  __shared__ int ls[256];
  const int b0 = blockIdx.x * 1024;
  const int t = threadIdx.x;
  int v[4];
  int s = 0;
#pragma unroll
  for (int i = 0; i < 4; ++i) {
    const int idx = b0 + t * 4 + i;
    v[i] = (idx < n) ? deg[idx] : 0;
    s += v[i];
  }
  ls[t] = s;
  __syncthreads();
  for (int off = 1; off < 256; off <<= 1) {
    const int x = (t >= off) ? ls[t - off] : 0;
    __syncthreads();
    ls[t] += x;
    __syncthreads();
  }
  int ex = ls[t] - s;  // exclusive over this block
#pragma unroll
  for (int i = 0; i < 4; ++i) {
    const int idx = b0 + t * 4 + i;
    if (idx < n) excl[idx] = ex;
    ex += v[i];
  }
  if (t == 255) partials[blockIdx.x] = ls[255];
}

// stage 2: serial exclusive scan of the (~98) chunk totals
__global__ void scan2(int* __restrict__ partials, int nb) {
  if (blockIdx.x == 0 && threadIdx.x == 0) {
    int run = 0;
    for (int i = 0; i < nb; ++i) { const int v = partials[i]; partials[i] = run; run += v; }
  }
}

// stage 3: add chunk offsets -> rowptr; also init cursor
__global__ __launch_bounds__(256) void scan3(const int* __restrict__ excl,
                                             const int* __restrict__ partials,
                                             int n, int* __restrict__ rowptr,
                                             int* __restrict__ cursor) {
  const int i = blockIdx.x * 256 + threadIdx.x;
  if (i < n) {
    const int v = excl[i] + partials[i >> 10];
    rowptr[i] = v;
    cursor[i] = v;
  }
  if (i == 0) rowptr[n] = EE;
}

__global__ __launch_bounds__(256) void fill_csr(const int* __restrict__ src,
                                                const int* __restrict__ dst,
                                                int* __restrict__ cursor,
                                                int* __restrict__ csr_src) {
  const int e = blockIdx.x * 256 + threadIdx.x;
  if (e < EE) {
    const int p = atomicAdd(&cursor[dst[e]], 1);
    csr_src[p] = src[e];
  }
}

// ---------------- per-destination attention: one wave per dst node
// lane l owns dims {2l, 2l+1}; head = l>>4 (16 lanes cover one 32-dim head).
// Online softmax: no score storage, no atomics, single coalesced agg write.
__global__ __launch_bounds__(256) void dst_attention(
    const float* __restrict__ Hq, const float* __restrict__ K,
    const float* __restrict__ V, const int* __restrict__ rowptr,
    const int* __restrict__ csr_src, float* __restrict__ agg) {
  const int w = blockIdx.x * 4 + (threadIdx.x >> 6);
  if (w >= NN) return;
  const int lane = threadIdx.x & 63;
  const int beg = rowptr[w], end = rowptr[w + 1];
  const float2 q = ((const float2*)(Hq + (size_t)w * DD))[lane];
  float m = -INFINITY, l = 0.0f;
  float ax = 0.0f, ay = 0.0f;
  for (int i = beg; i < end; ++i) {
    const int sidx = csr_src[i];
    const float2 k = ((const float2*)(K + (size_t)sidx * DD))[lane];
    float p = q.x * k.x + q.y * k.y;
    p += __shfl_xor(p, 1);
    p += __shfl_xor(p, 2);
    p += __shfl_xor(p, 4);
    p += __shfl_xor(p, 8);
    const float sc = p * 0.17677669529663689f;  // 1/sqrt(32)
    const float mn = fmaxf(m, sc);
    const float scale = __expf(m - mn);   // first iter: exp(-inf)=0
    const float wgt = __expf(sc - mn);
    const float2 v = ((const float2*)(V + (size_t)sidx * DD))[lane];
    l = l * scale + wgt;
    ax = ax * scale + wgt * v.x;
    ay = ay * scale + wgt * v.y;
    m = mn;
  }
  const float invl = (l > 0.0f) ? (1.0f / l) : 0.0f;
  float2 o;
  o.x = ax * invl;
  o.y = ay * invl;
  ((float2*)(agg + (size_t)w * DD))[lane] = o;
}

extern "C" void kernel_launch(void* const* d_in, const int* in_sizes, int n_in,
                              void* d_out, int out_size, void* d_ws, size_t ws_size,
                              hipStream_t stream) {
  const float* x_drug  = (const float*)d_in[0];
  const float* x_dis   = (const float*)d_in[1];
  const float* Wp_drug = (const float*)d_in[2];
  const float* bp_drug = (const float*)d_in[3];
  const float* Wp_dis  = (const float*)d_in[4];
  const float* bp_dis  = (const float*)d_in[5];
  const float* Wk_r0   = (const float*)d_in[6];
  const float* Wv_r0   = (const float*)d_in[7];
  const float* Wk_r1   = (const float*)d_in[8];
  const float* Wv_r1   = (const float*)d_in[9];
  const float* Wu_drug = (const float*)d_in[10];
  const float* bu_drug = (const float*)d_in[11];
  const float* Wu_dis  = (const float*)d_in[12];
  const float* bu_dis  = (const float*)d_in[13];
  const float* g_drug  = (const float*)d_in[14];
  const float* be_drug = (const float*)d_in[15];
  const float* g_dis   = (const float*)d_in[16];
  const float* be_dis  = (const float*)d_in[17];
  const int* ei_r0     = (const int*)d_in[18];
  const int* ei_r1     = (const int*)d_in[19];

  float* out = (float*)d_out;
  float* h_drug = out;
  float* h_dis  = out + (size_t)NN * DD;

  const size_t ND = (size_t)NN * DD;
  float* ws    = (float*)d_ws;
  float* Kbuf  = ws;                 // N*D
  float* Vbuf  = Kbuf + ND;          // N*D
  float* aggdr = Vbuf + ND;          // N*D
  float* aggdi = aggdr + ND;         // N*D
  int* ibase   = (int*)(aggdi + ND);
  int* deg     = ibase;              // N
  int* excl    = deg + NN;           // N
  int* rowptr  = excl + NN;          // N+1
  int* cursor  = rowptr + NN + 1;    // N
  int* partials= cursor + NN;        // 128
  int* csr_src = partials + 128;     // E

  const int gemm_blocks = (NN + 63) / 64;
  const int edge_blocks = (EE + 255) / 256;
  const int nchunks = (NN + 1023) / 1024;           // 98
  const int n256 = (NN + 255) / 256;                // 391
  const int attn_blocks = (NN + 3) / 4;             // 25000
  dim3 b256(256);

  // projections -> h in d_out
  gemm128<<<gemm_blocks, b256, 0, stream>>>(x_drug, Wp_drug, bp_drug, h_drug, NN);
  gemm128<<<gemm_blocks, b256, 0, stream>>>(x_dis,  Wp_dis,  bp_dis,  h_dis,  NN);

  // ---- relation 0: drug -> dis (K,V from h_drug; Q = h_dis; agg -> aggdi)
  gemm128<<<gemm_blocks, b256, 0, stream>>>(h_drug, Wk_r0, nullptr, Kbuf, NN);
  gemm128<<<gemm_blocks, b256, 0, stream>>>(h_drug, Wv_r0, nullptr, Vbuf, NN);
  hipMemsetAsync(deg, 0, NN * sizeof(int), stream);
  count_deg<<<edge_blocks, b256, 0, stream>>>(ei_r0 + EE, deg);
  scan1<<<nchunks, b256, 0, stream>>>(deg, excl, partials, NN);
  scan2<<<1, 64, 0, stream>>>(partials, nchunks);
  scan3<<<n256, b256, 0, stream>>>(excl, partials, NN, rowptr, cursor);
  fill_csr<<<edge_blocks, b256, 0, stream>>>(ei_r0, ei_r0 + EE, cursor, csr_src);
  dst_attention<<<attn_blocks, b256, 0, stream>>>(h_dis, Kbuf, Vbuf, rowptr, csr_src, aggdi);

  // ---- relation 1: dis -> drug (K,V from h_dis; Q = h_drug; agg -> aggdr)
  gemm128<<<gemm_blocks, b256, 0, stream>>>(h_dis, Wk_r1, nullptr, Kbuf, NN);
  gemm128<<<gemm_blocks, b256, 0, stream>>>(h_dis, Wv_r1, nullptr, Vbuf, NN);
  hipMemsetAsync(deg, 0, NN * sizeof(int), stream);
  count_deg<<<edge_blocks, b256, 0, stream>>>(ei_r1 + EE, deg);
  scan1<<<nchunks, b256, 0, stream>>>(deg, excl, partials, NN);
  scan2<<<1, 64, 0, stream>>>(partials, nchunks);
  scan3<<<n256, b256, 0, stream>>>(excl, partials, NN, rowptr, cursor);
  fill_csr<<<edge_blocks, b256, 0, stream>>>(ei_r1, ei_r1 + EE, cursor, csr_src);
  dst_attention<<<attn_blocks, b256, 0, stream>>>(h_drug, Kbuf, Vbuf, rowptr, csr_src, aggdr);

  // ---- update + LN + ReLU
  update_ln<<<gemm_blocks, b256, 0, stream>>>(h_drug, aggdr, Wu_drug, bu_drug, g_drug, be_drug, h_drug, NN);
  update_ln<<<gemm_blocks, b256, 0, stream>>>(h_dis,  aggdi, Wu_dis,  bu_dis,  g_dis,  be_dis,  h_dis,  NN);
}

// Round 3
// 519.927 us; speedup vs baseline: 12.5652x; 1.7090x over previous
//
#include <hip/hip_runtime.h>
#include <math.h>

#define NN 100000
#define EE 400000
#define DD 128

typedef __attribute__((ext_vector_type(8))) short bf16x8;
typedef __attribute__((ext_vector_type(4))) float f32x4;

__device__ __forceinline__ unsigned short f2bf(float f) {
  unsigned u = __float_as_uint(f);
  u += 0x7FFF + ((u >> 16) & 1);   // round-to-nearest-even
  return (unsigned short)(u >> 16);
}
__device__ __forceinline__ float bf2f(unsigned short u) {
  return __uint_as_float(((unsigned)u) << 16);
}

// ---- transpose + bf16-convert: O[c][k] = bf16(W[k][c]); 4 matrices, 1 block each
__global__ __launch_bounds__(256) void transpose_w(
    const float* __restrict__ w0, const float* __restrict__ w1,
    const float* __restrict__ w2, const float* __restrict__ w3,
    unsigned short* __restrict__ o0, unsigned short* __restrict__ o1,
    unsigned short* __restrict__ o2, unsigned short* __restrict__ o3) {
  const float* W; unsigned short* O;
  switch (blockIdx.x) {
    case 0: W = w0; O = o0; break;
    case 1: W = w1; O = o1; break;
    case 2: W = w2; O = o2; break;
    default: W = w3; O = o3; break;
  }
  const int t = threadIdx.x;
  const int c = t >> 1, kr = (t & 1) * 64;
  for (int k = 0; k < 64; ++k)
    O[c * DD + kr + k] = f2bf(W[(size_t)(kr + k) * DD + c]);
}

// ---- composite: O[c][k] = bf16(sum_j A[k][j]*B[j][c]); bo[c] = sum_j bp[j]*B[j][c]
__global__ __launch_bounds__(256) void composite_w(
    const float* __restrict__ Wp_dr, const float* __restrict__ bp_dr,
    const float* __restrict__ Wp_di, const float* __restrict__ bp_di,
    const float* __restrict__ Bk0, const float* __restrict__ Bv0,
    const float* __restrict__ Bk1, const float* __restrict__ Bv1,
    unsigned short* __restrict__ Ok0, float* __restrict__ bok0,
    unsigned short* __restrict__ Ov0, float* __restrict__ bov0,
    unsigned short* __restrict__ Ok1, float* __restrict__ bok1,
    unsigned short* __restrict__ Ov1, float* __restrict__ bov1) {
  const float* A; const float* bp; const float* B;
  unsigned short* O; float* bo;
  switch (blockIdx.x) {
    case 0: A = Wp_dr; bp = bp_dr; B = Bk0; O = Ok0; bo = bok0; break;
    case 1: A = Wp_dr; bp = bp_dr; B = Bv0; O = Ov0; bo = bov0; break;
    case 2: A = Wp_di; bp = bp_di; B = Bk1; O = Ok1; bo = bok1; break;
    default: A = Wp_di; bp = bp_di; B = Bv1; O = Ov1; bo = bov1; break;
  }
  __shared__ float BL[DD * DD];
  const int t = threadIdx.x;
  {
    const float4* B4 = (const float4*)B;
    float4* BL4 = (float4*)BL;
#pragma unroll
    for (int i = 0; i < 16; ++i) BL4[t + i * 256] = B4[t + i * 256];
  }
  __syncthreads();
  const int c = t >> 1, kr = (t & 1) * 64;
  for (int kidx = 0; kidx < 64; ++kidx) {
    const int k = kr + kidx;
    const float4* ar = (const float4*)(A + (size_t)k * DD);
    float s = 0.0f;
#pragma unroll 8
    for (int j4 = 0; j4 < 32; ++j4) {
      const float4 av = ar[j4];
      s += av.x * BL[(4 * j4 + 0) * DD + c] + av.y * BL[(4 * j4 + 1) * DD + c]
         + av.z * BL[(4 * j4 + 2) * DD + c] + av.w * BL[(4 * j4 + 3) * DD + c];
    }
    O[c * DD + k] = f2bf(s);
  }
  if (t < DD) {
    float s = 0.0f;
    for (int j = 0; j < DD; ++j) s += bp[j] * BL[j * DD + t];
    bo[t] = s;
  }
}

// stage one transposed-bf16 weight (32KB) into LDS with XOR swizzle
#define STAGE_W(SRC)                                                          \
  do {                                                                        \
    __syncthreads();                                                          \
    _Pragma("unroll") for (int i_ = threadIdx.x; i_ < 2048; i_ += 256) {      \
      const int L_ = i_ * 16;                                                 \
      *(float4*)((char*)WL + (L_ ^ (((L_ >> 8) & 7) << 4))) =                 \
          ((const float4*)(SRC))[i_];                                         \
    }                                                                         \
    __syncthreads();                                                          \
  } while (0)

// one wave computes 16 rows x 128 cols: D = A(16x128) @ Wt^T via 8x4 mfma
__device__ __forceinline__ void mfma_tile_store(
    const unsigned short* WL, const bf16x8* a, int lane, int rowbase,
    bool wvalid, const float* __restrict__ bias, float* __restrict__ outf,
    unsigned short* __restrict__ outb) {
  const int r0 = rowbase + (lane >> 4) * 4;
#pragma unroll
  for (int ni = 0; ni < 8; ++ni) {
    const int cl = ni * 16 + (lane & 15);
    f32x4 acc = {0.f, 0.f, 0.f, 0.f};
#pragma unroll
    for (int kk = 0; kk < 4; ++kk) {
      int boff = cl * 256 + kk * 64 + (lane >> 4) * 16;
      boff ^= (cl & 7) << 4;
      const bf16x8 b = *(const bf16x8*)((const char*)WL + boff);
      acc = __builtin_amdgcn_mfma_f32_16x16x32_bf16(a[kk], b, acc, 0, 0, 0);
    }
    if (wvalid) {
      const float bb = bias[cl];
      if (outf) {
#pragma unroll
        for (int r = 0; r < 4; ++r)
          outf[(size_t)(r0 + r) * DD + cl] = acc[r] + bb;
      } else {
#pragma unroll
        for (int r = 0; r < 4; ++r)
          outb[(size_t)(r0 + r) * DD + cl] = f2bf(acc[r] + bb);
      }
    }
  }
}

// ---- fused: h = x@Wp+bp (fp32), K = x@Wkc+bk (bf16), V = x@Wvc+bv (bf16)
__global__ __launch_bounds__(256) void fused_proj(
    const float* __restrict__ x,
    const unsigned short* __restrict__ Wpt, const float* __restrict__ bpv,
    const unsigned short* __restrict__ Wkt, const float* __restrict__ bkv,
    const unsigned short* __restrict__ Wvt, const float* __restrict__ bvv,
    float* __restrict__ h, unsigned short* __restrict__ K,
    unsigned short* __restrict__ V) {
  __shared__ unsigned short WL[DD * DD];
  const int tid = threadIdx.x, lane = tid & 63, wid = tid >> 6;
  const int rowbase = blockIdx.x * 64 + wid * 16;
  const bool wvalid = rowbase < NN;
  bf16x8 a[4];
  if (wvalid) {
    const int arow = rowbase + (lane & 15);
    const float* xr = x + (size_t)arow * DD + (lane >> 4) * 8;
#pragma unroll
    for (int kk = 0; kk < 4; ++kk) {
      const float4 f0 = *(const float4*)(xr + kk * 32);
      const float4 f1 = *(const float4*)(xr + kk * 32 + 4);
      a[kk][0] = (short)f2bf(f0.x); a[kk][1] = (short)f2bf(f0.y);
      a[kk][2] = (short)f2bf(f0.z); a[kk][3] = (short)f2bf(f0.w);
      a[kk][4] = (short)f2bf(f1.x); a[kk][5] = (short)f2bf(f1.y);
      a[kk][6] = (short)f2bf(f1.z); a[kk][7] = (short)f2bf(f1.w);
    }
  } else {
#pragma unroll
    for (int kk = 0; kk < 4; ++kk)
#pragma unroll
      for (int j = 0; j < 8; ++j) a[kk][j] = 0;
  }
  STAGE_W(Wpt);
  mfma_tile_store(WL, a, lane, rowbase, wvalid, bpv, h, nullptr);
  STAGE_W(Wkt);
  mfma_tile_store(WL, a, lane, rowbase, wvalid, bkv, nullptr, K);
  STAGE_W(Wvt);
  mfma_tile_store(WL, a, lane, rowbase, wvalid, bvv, nullptr, V);
}

// ---- fused update GEMM (bf16 agg @ Wu) + skip + LayerNorm + ReLU
__global__ __launch_bounds__(256) void update_ln2(
    const float* __restrict__ h, const unsigned short* __restrict__ agg,
    const unsigned short* __restrict__ Wut, const float* __restrict__ bu,
    const float* __restrict__ g, const float* __restrict__ be,
    float* __restrict__ out) {
  __shared__ unsigned short WL[DD * DD];
  const int tid = threadIdx.x, lane = tid & 63, wid = tid >> 6;
  const int rowbase = blockIdx.x * 64 + wid * 16;
  const bool wvalid = rowbase < NN;
  bf16x8 a[4];
  if (wvalid) {
    const int arow = rowbase + (lane & 15);
#pragma unroll
    for (int kk = 0; kk < 4; ++kk)
      a[kk] = *(const bf16x8*)(agg + (size_t)arow * DD + kk * 32 + (lane >> 4) * 8);
  } else {
#pragma unroll
    for (int kk = 0; kk < 4; ++kk)
#pragma unroll
      for (int j = 0; j < 8; ++j) a[kk][j] = 0;
  }
  STAGE_W(Wut);
  f32x4 acc[8];
  const int r0 = rowbase + (lane >> 4) * 4;
#pragma unroll
  for (int ni = 0; ni < 8; ++ni) {
    const int cl = ni * 16 + (lane & 15);
    acc[ni] = (f32x4){0.f, 0.f, 0.f, 0.f};
#pragma unroll
    for (int kk = 0; kk < 4; ++kk) {
      int boff = cl * 256 + kk * 64 + (lane >> 4) * 16;
      boff ^= (cl & 7) << 4;
      const bf16x8 b = *(const bf16x8*)((const char*)WL + boff);
      acc[ni] = __builtin_amdgcn_mfma_f32_16x16x32_bf16(a[kk], b, acc[ni], 0, 0, 0);
    }
  }
  if (!wvalid) return;
  // x = h + agg@Wu + bu
#pragma unroll
  for (int ni = 0; ni < 8; ++ni) {
    const int cl = ni * 16 + (lane & 15);
    const float bb = bu[cl];
#pragma unroll
    for (int r = 0; r < 4; ++r)
      acc[ni][r] += h[(size_t)(r0 + r) * DD + cl] + bb;
  }
  // LayerNorm stats: reduce over 8 in-lane cols x 16 lanes (lanes share rows)
  float mean[4], inv[4];
#pragma unroll
  for (int r = 0; r < 4; ++r) {
    float s = 0.f, q = 0.f;
#pragma unroll
    for (int ni = 0; ni < 8; ++ni) {
      const float v = acc[ni][r];
      s += v; q += v * v;
    }
    s += __shfl_xor(s, 1); q += __shfl_xor(q, 1);
    s += __shfl_xor(s, 2); q += __shfl_xor(q, 2);
    s += __shfl_xor(s, 4); q += __shfl_xor(q, 4);
    s += __shfl_xor(s, 8); q += __shfl_xor(q, 8);
    const float mu = s * (1.0f / 128.0f);
    mean[r] = mu;
    inv[r] = rsqrtf(q * (1.0f / 128.0f) - mu * mu + 1e-5f);
  }
#pragma unroll
  for (int ni = 0; ni < 8; ++ni) {
    const int cl = ni * 16 + (lane & 15);
    const float gv = g[cl], bev = be[cl];
#pragma unroll
    for (int r = 0; r < 4; ++r)
      out[(size_t)(r0 + r) * DD + cl] =
          fmaxf((acc[ni][r] - mean[r]) * inv[r] * gv + bev, 0.0f);
  }
}

// ---------------- CSR build ----------------
__global__ __launch_bounds__(256) void count_deg(const int* __restrict__ dst,
                                                 int* __restrict__ deg) {
  const int e = blockIdx.x * 256 + threadIdx.x;
  if (e < EE) atomicAdd(&deg[dst[e]], 1);
}

__global__ __launch_bounds__(256) void scan1(const int* __restrict__ deg,
                                             int* __restrict__ excl,
                                             int* __restrict__ partials, int n) {
  __shared__ int ls[256];
  const int b0 = blockIdx.x * 1024;
  const int t = threadIdx.x;
  int v[4];
  int s = 0;
#pragma unroll
  for (int i = 0; i < 4; ++i) {
    const int idx = b0 + t * 4 + i;
    v[i] = (idx < n) ? deg[idx] : 0;
    s += v[i];
  }
  ls[t] = s;
  __syncthreads();
  for (int off = 1; off < 256; off <<= 1) {
    const int x = (t >= off) ? ls[t - off] : 0;
    __syncthreads();
    ls[t] += x;
    __syncthreads();
  }
  int ex = ls[t] - s;
#pragma unroll
  for (int i = 0; i < 4; ++i) {
    const int idx = b0 + t * 4 + i;
    if (idx < n) excl[idx] = ex;
    ex += v[i];
  }
  if (t == 255) partials[blockIdx.x] = ls[255];
}

__global__ void scan2(int* __restrict__ partials, int nb) {
  if (blockIdx.x == 0 && threadIdx.x == 0) {
    int run = 0;
    for (int i = 0; i < nb; ++i) { const int v = partials[i]; partials[i] = run; run += v; }
  }
}

__global__ __launch_bounds__(256) void scan3(const int* __restrict__ excl,
                                             const int* __restrict__ partials,
                                             int n, int* __restrict__ rowptr,
                                             int* __restrict__ cursor) {
  const int i = blockIdx.x * 256 + threadIdx.x;
  if (i < n) {
    const int v = excl[i] + partials[i >> 10];
    rowptr[i] = v;
    cursor[i] = v;
  }
  if (i == 0) rowptr[n] = EE;
}

__global__ __launch_bounds__(256) void fill_csr(const int* __restrict__ src,
                                                const int* __restrict__ dst,
                                                int* __restrict__ cursor,
                                                int* __restrict__ csr_src) {
  const int e = blockIdx.x * 256 + threadIdx.x;
  if (e < EE) {
    const int p = atomicAdd(&cursor[dst[e]], 1);
    csr_src[p] = src[e];
  }
}

// ---- per-destination attention, one wave per node, bf16 K/V, bf16 agg out
__global__ __launch_bounds__(256) void dst_attention(
    const float* __restrict__ Hq, const unsigned short* __restrict__ K,
    const unsigned short* __restrict__ V, const int* __restrict__ rowptr,
    const int* __restrict__ csr_src, unsigned short* __restrict__ agg) {
  const int w = blockIdx.x * 4 + (threadIdx.x >> 6);
  if (w >= NN) return;
  const int lane = threadIdx.x & 63;
  const int beg = rowptr[w], end = rowptr[w + 1];
  const float2 q = ((const float2*)(Hq + (size_t)w * DD))[lane];
  float m = -INFINITY, l = 0.0f;
  float ax = 0.0f, ay = 0.0f;
  for (int i = beg; i < end; ++i) {
    const int sidx = csr_src[i];
    const unsigned kp = ((const unsigned*)(K + (size_t)sidx * DD))[lane];
    const float kx = bf2f((unsigned short)kp);
    const float ky = bf2f((unsigned short)(kp >> 16));
    float p = q.x * kx + q.y * ky;
    p += __shfl_xor(p, 1);
    p += __shfl_xor(p, 2);
    p += __shfl_xor(p, 4);
    p += __shfl_xor(p, 8);
    const float sc = p * 0.17677669529663689f;  // 1/sqrt(32)
    const float mn = fmaxf(m, sc);
    const float scale = __expf(m - mn);
    const float wgt = __expf(sc - mn);
    const unsigned vp = ((const unsigned*)(V + (size_t)sidx * DD))[lane];
    l = l * scale + wgt;
    ax = ax * scale + wgt * bf2f((unsigned short)vp);
    ay = ay * scale + wgt * bf2f((unsigned short)(vp >> 16));
    m = mn;
  }
  const float invl = (l > 0.0f) ? (1.0f / l) : 0.0f;
  const unsigned o = (unsigned)f2bf(ax * invl) | ((unsigned)f2bf(ay * invl) << 16);
  ((unsigned*)(agg + (size_t)w * DD))[lane] = o;
}

extern "C" void kernel_launch(void* const* d_in, const int* in_sizes, int n_in,
                              void* d_out, int out_size, void* d_ws, size_t ws_size,
                              hipStream_t stream) {
  const float* x_drug  = (const float*)d_in[0];
  const float* x_dis   = (const float*)d_in[1];
  const float* Wp_drug = (const float*)d_in[2];
  const float* bp_drug = (const float*)d_in[3];
  const float* Wp_dis  = (const float*)d_in[4];
  const float* bp_dis  = (const float*)d_in[5];
  const float* Wk_r0   = (const float*)d_in[6];
  const float* Wv_r0   = (const float*)d_in[7];
  const float* Wk_r1   = (const float*)d_in[8];
  const float* Wv_r1   = (const float*)d_in[9];
  const float* Wu_drug = (const float*)d_in[10];
  const float* bu_drug = (const float*)d_in[11];
  const float* Wu_dis  = (const float*)d_in[12];
  const float* bu_dis  = (const float*)d_in[13];
  const float* g_drug  = (const float*)d_in[14];
  const float* be_drug = (const float*)d_in[15];
  const float* g_dis   = (const float*)d_in[16];
  const float* be_dis  = (const float*)d_in[17];
  const int* ei_r0     = (const int*)d_in[18];
  const int* ei_r1     = (const int*)d_in[19];

  float* out = (float*)d_out;
  float* h_drug = out;
  float* h_dis  = out + (size_t)NN * DD;

  const size_t ND = (size_t)NN * DD;
  char* w = (char*)d_ws;
  unsigned short* Kr0  = (unsigned short*)w; w += ND * 2;
  unsigned short* Vr0  = (unsigned short*)w; w += ND * 2;
  unsigned short* Kr1  = (unsigned short*)w; w += ND * 2;
  unsigned short* Vr1  = (unsigned short*)w; w += ND * 2;
  unsigned short* agdr = (unsigned short*)w; w += ND * 2;
  unsigned short* agdi = (unsigned short*)w; w += ND * 2;
  unsigned short* Wpt_dr = (unsigned short*)w; w += DD * DD * 2;
  unsigned short* Wpt_di = (unsigned short*)w; w += DD * DD * 2;
  unsigned short* Wut_dr = (unsigned short*)w; w += DD * DD * 2;
  unsigned short* Wut_di = (unsigned short*)w; w += DD * DD * 2;
  unsigned short* Wkt0 = (unsigned short*)w; w += DD * DD * 2;
  unsigned short* Wvt0 = (unsigned short*)w; w += DD * DD * 2;
  unsigned short* Wkt1 = (unsigned short*)w; w += DD * DD * 2;
  unsigned short* Wvt1 = (unsigned short*)w; w += DD * DD * 2;
  float* bk0 = (float*)w; w += DD * 4;
  float* bv0 = (float*)w; w += DD * 4;
  float* bk1 = (float*)w; w += DD * 4;
  float* bv1 = (float*)w; w += DD * 4;
  int* deg      = (int*)w; w += NN * 4;
  int* excl     = (int*)w; w += NN * 4;
  int* rowptr   = (int*)w; w += (NN + 1) * 4;
  int* cursor   = (int*)w; w += NN * 4;
  int* partials = (int*)w; w += 128 * 4;
  int* csr_src  = (int*)w; w += EE * 4;

  const int gemm_blocks = (NN + 63) / 64;      // 1563
  const int edge_blocks = (EE + 255) / 256;
  const int nchunks = (NN + 1023) / 1024;
  const int n256 = (NN + 255) / 256;
  const int attn_blocks = (NN + 3) / 4;
  dim3 b256(256);

  // weight prep
  transpose_w<<<4, b256, 0, stream>>>(Wp_drug, Wp_dis, Wu_drug, Wu_dis,
                                      Wpt_dr, Wpt_di, Wut_dr, Wut_di);
  composite_w<<<4, b256, 0, stream>>>(Wp_drug, bp_drug, Wp_dis, bp_dis,
                                      Wk_r0, Wv_r0, Wk_r1, Wv_r1,
                                      Wkt0, bk0, Wvt0, bv0, Wkt1, bk1, Wvt1, bv1);

  // fused projections: h (fp32, in d_out) + K,V (bf16) straight from x
  fused_proj<<<gemm_blocks, b256, 0, stream>>>(x_drug, Wpt_dr, bp_drug,
                                               Wkt0, bk0, Wvt0, bv0,
                                               h_drug, Kr0, Vr0);
  fused_proj<<<gemm_blocks, b256, 0, stream>>>(x_dis, Wpt_di, bp_dis,
                                               Wkt1, bk1, Wvt1, bv1,
                                               h_dis, Kr1, Vr1);

  // relation 0: drug -> dis
  hipMemsetAsync(deg, 0, NN * sizeof(int), stream);
  count_deg<<<edge_blocks, b256, 0, stream>>>(ei_r0 + EE, deg);
  scan1<<<nchunks, b256, 0, stream>>>(deg, excl, partials, NN);
  scan2<<<1, 64, 0, stream>>>(partials, nchunks);
  scan3<<<n256, b256, 0, stream>>>(excl, partials, NN, rowptr, cursor);
  fill_csr<<<edge_blocks, b256, 0, stream>>>(ei_r0, ei_r0 + EE, cursor, csr_src);
  dst_attention<<<attn_blocks, b256, 0, stream>>>(h_dis, Kr0, Vr0, rowptr, csr_src, agdi);

  // relation 1: dis -> drug
  hipMemsetAsync(deg, 0, NN * sizeof(int), stream);
  count_deg<<<edge_blocks, b256, 0, stream>>>(ei_r1 + EE, deg);
  scan1<<<nchunks, b256, 0, stream>>>(deg, excl, partials, NN);
  scan2<<<1, 64, 0, stream>>>(partials, nchunks);
  scan3<<<n256, b256, 0, stream>>>(excl, partials, NN, rowptr, cursor);
  fill_csr<<<edge_blocks, b256, 0, stream>>>(ei_r1, ei_r1 + EE, cursor, csr_src);
  dst_attention<<<attn_blocks, b256, 0, stream>>>(h_drug, Kr1, Vr1, rowptr, csr_src, agdr);

  // update + LayerNorm + ReLU (in place over h in d_out)
  update_ln2<<<gemm_blocks, b256, 0, stream>>>(h_drug, agdr, Wut_dr, bu_drug,
                                               g_drug, be_drug, h_drug);
  update_ln2<<<gemm_blocks, b256, 0, stream>>>(h_dis, agdi, Wut_di, bu_dis,
                                               g_dis, be_dis, h_dis);
}

// Round 4
// 361.292 us; speedup vs baseline: 18.0823x; 1.4391x over previous
//
#include <hip/hip_runtime.h>
#include <math.h>

#define NN 100000
#define EE 400000
#define DD 128

typedef __attribute__((ext_vector_type(8))) short bf16x8;
typedef __attribute__((ext_vector_type(4))) float f32x4;

__device__ __forceinline__ unsigned short f2bf(float f) {
  unsigned u = __float_as_uint(f);
  u += 0x7FFF + ((u >> 16) & 1);   // round-to-nearest-even
  return (unsigned short)(u >> 16);
}
__device__ __forceinline__ float bf2f(unsigned short u) {
  return __uint_as_float(((unsigned)u) << 16);
}

// ---- one-shot weight prep: 4 transposes + 4 composites + 4 bias composites
// grid = 514 blocks x 256; one output element per thread (all L2-resident).
__global__ __launch_bounds__(256) void prep_weights(
    const float* __restrict__ Wp_dr, const float* __restrict__ bp_dr,
    const float* __restrict__ Wp_di, const float* __restrict__ bp_di,
    const float* __restrict__ Wu_dr, const float* __restrict__ Wu_di,
    const float* __restrict__ Bk0, const float* __restrict__ Bv0,
    const float* __restrict__ Bk1, const float* __restrict__ Bv1,
    unsigned short* __restrict__ Wpt_dr, unsigned short* __restrict__ Wpt_di,
    unsigned short* __restrict__ Wut_dr, unsigned short* __restrict__ Wut_di,
    unsigned short* __restrict__ Wkt0, float* __restrict__ bk0,
    unsigned short* __restrict__ Wvt0, float* __restrict__ bv0,
    unsigned short* __restrict__ Wkt1, float* __restrict__ bk1,
    unsigned short* __restrict__ Wvt1, float* __restrict__ bv1) {
  const int b = blockIdx.x, t = threadIdx.x;
  if (b < 256) {
    // transpose+bf16: O[c][k] = bf16(W[k][c])
    const int id = b * 256 + t;
    const int m = id >> 14, rem = id & 16383, k = rem & 127, c = rem >> 7;
    const float* W = (m == 0) ? Wp_dr : (m == 1) ? Wp_di : (m == 2) ? Wu_dr : Wu_di;
    unsigned short* O = (m == 0) ? Wpt_dr : (m == 1) ? Wpt_di : (m == 2) ? Wut_dr : Wut_di;
    O[c * DD + k] = f2bf(W[(size_t)k * DD + c]);
  } else if (b < 512) {
    // composite: O[c][k] = bf16(sum_j A[k][j] * B[j][c])
    const int id = (b - 256) * 256 + t;
    const int m = id >> 14, rem = id & 16383, k = rem & 127, c = rem >> 7;
    const float* A = (m < 2) ? Wp_dr : Wp_di;
    const float* B = (m == 0) ? Bk0 : (m == 1) ? Bv0 : (m == 2) ? Bk1 : Bv1;
    unsigned short* O = (m == 0) ? Wkt0 : (m == 1) ? Wvt0 : (m == 2) ? Wkt1 : Wvt1;
    const float4* a4 = (const float4*)(A + (size_t)k * DD);
    float s = 0.0f;
#pragma unroll 8
    for (int j4 = 0; j4 < 32; ++j4) {
      const float4 av = a4[j4];
      s += av.x * B[(4 * j4 + 0) * DD + c] + av.y * B[(4 * j4 + 1) * DD + c]
         + av.z * B[(4 * j4 + 2) * DD + c] + av.w * B[(4 * j4 + 3) * DD + c];
    }
    O[c * DD + k] = f2bf(s);
  } else {
    // bias composites: bo[c] = sum_j bp[j] * B[j][c]   (512 elements)
    const int id = (b - 512) * 256 + t;
    if (id < 512) {
      const int m = id >> 7, c = id & 127;
      const float* bp = (m < 2) ? bp_dr : bp_di;
      const float* B = (m == 0) ? Bk0 : (m == 1) ? Bv0 : (m == 2) ? Bk1 : Bv1;
      float* bo = (m == 0) ? bk0 : (m == 1) ? bv0 : (m == 2) ? bk1 : bv1;
      float s = 0.0f;
#pragma unroll 8
      for (int j = 0; j < DD; ++j) s += bp[j] * B[j * DD + c];
      bo[c] = s;
    }
  }
}

// stage one transposed-bf16 weight (32KB) into LDS with XOR swizzle
#define STAGE_W(SRC)                                                          \
  do {                                                                        \
    __syncthreads();                                                          \
    _Pragma("unroll") for (int i_ = threadIdx.x; i_ < 2048; i_ += 256) {      \
      const int L_ = i_ * 16;                                                 \
      *(float4*)((char*)WL + (L_ ^ (((L_ >> 8) & 7) << 4))) =                 \
          ((const float4*)(SRC))[i_];                                         \
    }                                                                         \
    __syncthreads();                                                          \
  } while (0)

// one wave computes 16 rows x 128 cols: D = A(16x128) @ Wt^T via 8x4 mfma
__device__ __forceinline__ void mfma_tile_store(
    const unsigned short* WL, const bf16x8* a, int lane, int rowbase,
    bool wvalid, const float* __restrict__ bias, float* __restrict__ outf,
    unsigned short* __restrict__ outb) {
  const int r0 = rowbase + (lane >> 4) * 4;
#pragma unroll
  for (int ni = 0; ni < 8; ++ni) {
    const int cl = ni * 16 + (lane & 15);
    f32x4 acc = {0.f, 0.f, 0.f, 0.f};
#pragma unroll
    for (int kk = 0; kk < 4; ++kk) {
      int boff = cl * 256 + kk * 64 + (lane >> 4) * 16;
      boff ^= (cl & 7) << 4;
      const bf16x8 bb = *(const bf16x8*)((const char*)WL + boff);
      acc = __builtin_amdgcn_mfma_f32_16x16x32_bf16(a[kk], bb, acc, 0, 0, 0);
    }
    if (wvalid) {
      const float bv = bias[cl];
      if (outf) {
#pragma unroll
        for (int r = 0; r < 4; ++r)
          outf[(size_t)(r0 + r) * DD + cl] = acc[r] + bv;
      } else {
#pragma unroll
        for (int r = 0; r < 4; ++r)
          outb[(size_t)(r0 + r) * DD + cl] = f2bf(acc[r] + bv);
      }
    }
  }
}

// ---- fused (both types in one launch): h = x@Wp+bp (fp32), K,V (bf16)
__global__ __launch_bounds__(256) void fused_proj(
    const float* __restrict__ x0, const unsigned short* __restrict__ Wpt0,
    const float* __restrict__ bp0, const unsigned short* __restrict__ Wkta,
    const float* __restrict__ bka, const unsigned short* __restrict__ Wvta,
    const float* __restrict__ bva, float* __restrict__ h0,
    unsigned short* __restrict__ K0, unsigned short* __restrict__ V0,
    const float* __restrict__ x1, const unsigned short* __restrict__ Wpt1,
    const float* __restrict__ bp1, const unsigned short* __restrict__ Wktb,
    const float* __restrict__ bkb, const unsigned short* __restrict__ Wvtb,
    const float* __restrict__ bvb, float* __restrict__ h1,
    unsigned short* __restrict__ K1, unsigned short* __restrict__ V1, int half) {
  __shared__ unsigned short WL[DD * DD];
  int bid = blockIdx.x;
  const bool second = bid >= half;
  if (second) bid -= half;
  const float* x = second ? x1 : x0;
  const unsigned short* Wpt = second ? Wpt1 : Wpt0;
  const float* bpv = second ? bp1 : bp0;
  const unsigned short* Wkt = second ? Wktb : Wkta;
  const float* bkv = second ? bkb : bka;
  const unsigned short* Wvt = second ? Wvtb : Wvta;
  const float* bvv = second ? bvb : bva;
  float* h = second ? h1 : h0;
  unsigned short* K = second ? K1 : K0;
  unsigned short* V = second ? V1 : V0;

  const int tid = threadIdx.x, lane = tid & 63, wid = tid >> 6;
  const int rowbase = bid * 64 + wid * 16;
  const bool wvalid = rowbase < NN;
  bf16x8 a[4];
  if (wvalid) {
    const int arow = rowbase + (lane & 15);
    const float* xr = x + (size_t)arow * DD + (lane >> 4) * 8;
#pragma unroll
    for (int kk = 0; kk < 4; ++kk) {
      const float4 f0 = *(const float4*)(xr + kk * 32);
      const float4 f1 = *(const float4*)(xr + kk * 32 + 4);
      a[kk][0] = (short)f2bf(f0.x); a[kk][1] = (short)f2bf(f0.y);
      a[kk][2] = (short)f2bf(f0.z); a[kk][3] = (short)f2bf(f0.w);
      a[kk][4] = (short)f2bf(f1.x); a[kk][5] = (short)f2bf(f1.y);
      a[kk][6] = (short)f2bf(f1.z); a[kk][7] = (short)f2bf(f1.w);
    }
  } else {
#pragma unroll
    for (int kk = 0; kk < 4; ++kk)
#pragma unroll
      for (int j = 0; j < 8; ++j) a[kk][j] = 0;
  }
  STAGE_W(Wpt);
  mfma_tile_store(WL, a, lane, rowbase, wvalid, bpv, h, nullptr);
  STAGE_W(Wkt);
  mfma_tile_store(WL, a, lane, rowbase, wvalid, bkv, nullptr, K);
  STAGE_W(Wvt);
  mfma_tile_store(WL, a, lane, rowbase, wvalid, bvv, nullptr, V);
}

// ---- fused update GEMM (bf16 agg @ Wu) + skip + LayerNorm + ReLU, both types
__global__ __launch_bounds__(256) void update_ln2(
    const float* __restrict__ ha, const unsigned short* __restrict__ agga,
    const unsigned short* __restrict__ Wuta, const float* __restrict__ bua,
    const float* __restrict__ ga, const float* __restrict__ bea,
    float* __restrict__ outa,
    const float* __restrict__ hb, const unsigned short* __restrict__ aggb,
    const unsigned short* __restrict__ Wutb, const float* __restrict__ bub,
    const float* __restrict__ gb, const float* __restrict__ beb,
    float* __restrict__ outb, int half) {
  __shared__ unsigned short WL[DD * DD];
  int bid = blockIdx.x;
  const bool second = bid >= half;
  if (second) bid -= half;
  const float* h = second ? hb : ha;
  const unsigned short* agg = second ? aggb : agga;
  const unsigned short* Wut = second ? Wutb : Wuta;
  const float* bu = second ? bub : bua;
  const float* g = second ? gb : ga;
  const float* be = second ? beb : bea;
  float* out = second ? outb : outa;

  const int tid = threadIdx.x, lane = tid & 63, wid = tid >> 6;
  const int rowbase = bid * 64 + wid * 16;
  const bool wvalid = rowbase < NN;
  bf16x8 a[4];
  if (wvalid) {
    const int arow = rowbase + (lane & 15);
#pragma unroll
    for (int kk = 0; kk < 4; ++kk)
      a[kk] = *(const bf16x8*)(agg + (size_t)arow * DD + kk * 32 + (lane >> 4) * 8);
  } else {
#pragma unroll
    for (int kk = 0; kk < 4; ++kk)
#pragma unroll
      for (int j = 0; j < 8; ++j) a[kk][j] = 0;
  }
  STAGE_W(Wut);
  f32x4 acc[8];
  const int r0 = rowbase + (lane >> 4) * 4;
#pragma unroll
  for (int ni = 0; ni < 8; ++ni) {
    const int cl = ni * 16 + (lane & 15);
    acc[ni] = (f32x4){0.f, 0.f, 0.f, 0.f};
#pragma unroll
    for (int kk = 0; kk < 4; ++kk) {
      int boff = cl * 256 + kk * 64 + (lane >> 4) * 16;
      boff ^= (cl & 7) << 4;
      const bf16x8 bb = *(const bf16x8*)((const char*)WL + boff);
      acc[ni] = __builtin_amdgcn_mfma_f32_16x16x32_bf16(a[kk], bb, acc[ni], 0, 0, 0);
    }
  }
  if (!wvalid) return;
#pragma unroll
  for (int ni = 0; ni < 8; ++ni) {
    const int cl = ni * 16 + (lane & 15);
    const float bv = bu[cl];
#pragma unroll
    for (int r = 0; r < 4; ++r)
      acc[ni][r] += h[(size_t)(r0 + r) * DD + cl] + bv;
  }
  float mean[4], inv[4];
#pragma unroll
  for (int r = 0; r < 4; ++r) {
    float s = 0.f, q = 0.f;
#pragma unroll
    for (int ni = 0; ni < 8; ++ni) {
      const float v = acc[ni][r];
      s += v; q += v * v;
    }
    s += __shfl_xor(s, 1); q += __shfl_xor(q, 1);
    s += __shfl_xor(s, 2); q += __shfl_xor(q, 2);
    s += __shfl_xor(s, 4); q += __shfl_xor(q, 4);
    s += __shfl_xor(s, 8); q += __shfl_xor(q, 8);
    const float mu = s * (1.0f / 128.0f);
    mean[r] = mu;
    inv[r] = rsqrtf(q * (1.0f / 128.0f) - mu * mu + 1e-5f);
  }
#pragma unroll
  for (int ni = 0; ni < 8; ++ni) {
    const int cl = ni * 16 + (lane & 15);
    const float gv = g[cl], bev = be[cl];
#pragma unroll
    for (int r = 0; r < 4; ++r)
      out[(size_t)(r0 + r) * DD + cl] =
          fmaxf((acc[ni][r] - mean[r]) * inv[r] * gv + bev, 0.0f);
  }
}

// ---------------- combined CSR build over both relations (2N nodes, 2E edges)
__global__ __launch_bounds__(256) void count_deg2(const int* __restrict__ ei0,
                                                  const int* __restrict__ ei1,
                                                  int* __restrict__ deg) {
  const int e = blockIdx.x * 256 + threadIdx.x;
  if (e >= 2 * EE) return;
  const int d = (e < EE) ? ei0[EE + e] : (NN + ei1[e]);  // ei1[EE+(e-EE)]
  atomicAdd(&deg[d], 1);
}

__global__ __launch_bounds__(256) void scan1(const int* __restrict__ deg,
                                             int* __restrict__ excl,
                                             int* __restrict__ partials, int n) {
  __shared__ int ls[256];
  const int b0 = blockIdx.x * 1024;
  const int t = threadIdx.x;
  int v[4];
  int s = 0;
#pragma unroll
  for (int i = 0; i < 4; ++i) {
    const int idx = b0 + t * 4 + i;
    v[i] = (idx < n) ? deg[idx] : 0;
    s += v[i];
  }
  ls[t] = s;
  __syncthreads();
  for (int off = 1; off < 256; off <<= 1) {
    const int x = (t >= off) ? ls[t - off] : 0;
    __syncthreads();
    ls[t] += x;
    __syncthreads();
  }
  int ex = ls[t] - s;
#pragma unroll
  for (int i = 0; i < 4; ++i) {
    const int idx = b0 + t * 4 + i;
    if (idx < n) excl[idx] = ex;
    ex += v[i];
  }
  if (t == 255) partials[blockIdx.x] = ls[255];
}

__global__ __launch_bounds__(256) void scan2(int* __restrict__ partials, int nb) {
  __shared__ int ls[256];
  const int t = threadIdx.x;
  const int v = (t < nb) ? partials[t] : 0;
  ls[t] = v;
  __syncthreads();
  for (int off = 1; off < 256; off <<= 1) {
    const int x = (t >= off) ? ls[t - off] : 0;
    __syncthreads();
    ls[t] += x;
    __syncthreads();
  }
  if (t < nb) partials[t] = ls[t] - v;
}

__global__ __launch_bounds__(256) void scan3(const int* __restrict__ excl,
                                             const int* __restrict__ partials,
                                             int n, int* __restrict__ rowptr,
                                             int* __restrict__ cursor) {
  const int i = blockIdx.x * 256 + threadIdx.x;
  if (i < n) {
    const int v = excl[i] + partials[i >> 10];
    rowptr[i] = v;
    cursor[i] = v;
  }
  if (i == 0) rowptr[n] = 2 * EE;
}

__global__ __launch_bounds__(256) void fill_csr2(const int* __restrict__ ei0,
                                                 const int* __restrict__ ei1,
                                                 int* __restrict__ cursor,
                                                 int* __restrict__ csr_src) {
  const int e = blockIdx.x * 256 + threadIdx.x;
  if (e >= 2 * EE) return;
  int s, d;
  if (e < EE) { s = ei0[e]; d = ei0[EE + e]; }
  else        { s = ei1[e - EE]; d = NN + ei1[e]; }
  const int p = atomicAdd(&cursor[d], 1);
  csr_src[p] = s;
}

// ---- per-destination attention, both relations in one launch; one wave/node
__global__ __launch_bounds__(256) void dst_attention(
    const float* __restrict__ Hq0, const unsigned short* __restrict__ K0,
    const unsigned short* __restrict__ V0, unsigned short* __restrict__ agg0,
    const float* __restrict__ Hq1, const unsigned short* __restrict__ K1,
    const unsigned short* __restrict__ V1, unsigned short* __restrict__ agg1,
    const int* __restrict__ rowptr, const int* __restrict__ csr_src) {
  const int gw = blockIdx.x * 4 + (threadIdx.x >> 6);
  if (gw >= 2 * NN) return;
  const bool rel1 = gw >= NN;
  const int node = rel1 ? gw - NN : gw;
  const float* Hq = rel1 ? Hq1 : Hq0;
  const unsigned short* K = rel1 ? K1 : K0;
  const unsigned short* V = rel1 ? V1 : V0;
  unsigned short* agg = rel1 ? agg1 : agg0;

  const int lane = threadIdx.x & 63;
  const int beg = rowptr[gw], end = rowptr[gw + 1];
  const float2 q = ((const float2*)(Hq + (size_t)node * DD))[lane];
  float m = -INFINITY, l = 0.0f;
  float ax = 0.0f, ay = 0.0f;
  for (int i = beg; i < end; ++i) {
    const int sidx = csr_src[i];
    const unsigned kp = ((const unsigned*)(K + (size_t)sidx * DD))[lane];
    const float kx = bf2f((unsigned short)kp);
    const float ky = bf2f((unsigned short)(kp >> 16));
    float p = q.x * kx + q.y * ky;
    p += __shfl_xor(p, 1);
    p += __shfl_xor(p, 2);
    p += __shfl_xor(p, 4);
    p += __shfl_xor(p, 8);
    const float sc = p * 0.17677669529663689f;  // 1/sqrt(32)
    const float mn = fmaxf(m, sc);
    const float scale = __expf(m - mn);
    const float wgt = __expf(sc - mn);
    const unsigned vp = ((const unsigned*)(V + (size_t)sidx * DD))[lane];
    l = l * scale + wgt;
    ax = ax * scale + wgt * bf2f((unsigned short)vp);
    ay = ay * scale + wgt * bf2f((unsigned short)(vp >> 16));
    m = mn;
  }
  const float invl = (l > 0.0f) ? (1.0f / l) : 0.0f;
  const unsigned o = (unsigned)f2bf(ax * invl) | ((unsigned)f2bf(ay * invl) << 16);
  ((unsigned*)(agg + (size_t)node * DD))[lane] = o;
}

extern "C" void kernel_launch(void* const* d_in, const int* in_sizes, int n_in,
                              void* d_out, int out_size, void* d_ws, size_t ws_size,
                              hipStream_t stream) {
  const float* x_drug  = (const float*)d_in[0];
  const float* x_dis   = (const float*)d_in[1];
  const float* Wp_drug = (const float*)d_in[2];
  const float* bp_drug = (const float*)d_in[3];
  const float* Wp_dis  = (const float*)d_in[4];
  const float* bp_dis  = (const float*)d_in[5];
  const float* Wk_r0   = (const float*)d_in[6];
  const float* Wv_r0   = (const float*)d_in[7];
  const float* Wk_r1   = (const float*)d_in[8];
  const float* Wv_r1   = (const float*)d_in[9];
  const float* Wu_drug = (const float*)d_in[10];
  const float* bu_drug = (const float*)d_in[11];
  const float* Wu_dis  = (const float*)d_in[12];
  const float* bu_dis  = (const float*)d_in[13];
  const float* g_drug  = (const float*)d_in[14];
  const float* be_drug = (const float*)d_in[15];
  const float* g_dis   = (const float*)d_in[16];
  const float* be_dis  = (const float*)d_in[17];
  const int* ei_r0     = (const int*)d_in[18];
  const int* ei_r1     = (const int*)d_in[19];

  float* out = (float*)d_out;
  float* h_drug = out;
  float* h_dis  = out + (size_t)NN * DD;

  const size_t ND = (size_t)NN * DD;
  char* w = (char*)d_ws;
  unsigned short* Kr0  = (unsigned short*)w; w += ND * 2;
  unsigned short* Vr0  = (unsigned short*)w; w += ND * 2;
  unsigned short* Kr1  = (unsigned short*)w; w += ND * 2;
  unsigned short* Vr1  = (unsigned short*)w; w += ND * 2;
  unsigned short* agdr = (unsigned short*)w; w += ND * 2;
  unsigned short* agdi = (unsigned short*)w; w += ND * 2;
  unsigned short* Wpt_dr = (unsigned short*)w; w += DD * DD * 2;
  unsigned short* Wpt_di = (unsigned short*)w; w += DD * DD * 2;
  unsigned short* Wut_dr = (unsigned short*)w; w += DD * DD * 2;
  unsigned short* Wut_di = (unsigned short*)w; w += DD * DD * 2;
  unsigned short* Wkt0 = (unsigned short*)w; w += DD * DD * 2;
  unsigned short* Wvt0 = (unsigned short*)w; w += DD * DD * 2;
  unsigned short* Wkt1 = (unsigned short*)w; w += DD * DD * 2;
  unsigned short* Wvt1 = (unsigned short*)w; w += DD * DD * 2;
  float* bk0 = (float*)w; w += DD * 4;
  float* bv0 = (float*)w; w += DD * 4;
  float* bk1 = (float*)w; w += DD * 4;
  float* bv1 = (float*)w; w += DD * 4;
  int* deg      = (int*)w; w += 2 * NN * 4;
  int* excl     = (int*)w; w += 2 * NN * 4;
  int* rowptr   = (int*)w; w += (2 * NN + 1) * 4;
  int* cursor   = (int*)w; w += 2 * NN * 4;
  int* partials = (int*)w; w += 256 * 4;
  int* csr_src  = (int*)w; w += 2 * EE * 4;

  const int gemm_blocks = (NN + 63) / 64;            // 1563
  const int edge_blocks2 = (2 * EE + 255) / 256;     // 3125
  const int nchunks = (2 * NN + 1023) / 1024;        // 196
  const int n256 = (2 * NN + 255) / 256;             // 782
  const int attn_blocks = (2 * NN + 3) / 4;          // 50000
  dim3 b256(256);

  // weight prep (one launch, fully parallel)
  prep_weights<<<514, b256, 0, stream>>>(
      Wp_drug, bp_drug, Wp_dis, bp_dis, Wu_drug, Wu_dis,
      Wk_r0, Wv_r0, Wk_r1, Wv_r1,
      Wpt_dr, Wpt_di, Wut_dr, Wut_di,
      Wkt0, bk0, Wvt0, bv0, Wkt1, bk1, Wvt1, bv1);

  // fused projections, both node types
  fused_proj<<<2 * gemm_blocks, b256, 0, stream>>>(
      x_drug, Wpt_dr, bp_drug, Wkt0, bk0, Wvt0, bv0, h_drug, Kr0, Vr0,
      x_dis,  Wpt_di, bp_dis,  Wkt1, bk1, Wvt1, bv1, h_dis,  Kr1, Vr1,
      gemm_blocks);

  // combined CSR build (rel0 nodes 0..N-1 = dis dst; rel1 nodes N..2N-1 = drug dst)
  hipMemsetAsync(deg, 0, 2 * NN * sizeof(int), stream);
  count_deg2<<<edge_blocks2, b256, 0, stream>>>(ei_r0, ei_r1, deg);
  scan1<<<nchunks, b256, 0, stream>>>(deg, excl, partials, 2 * NN);
  scan2<<<1, b256, 0, stream>>>(partials, nchunks);
  scan3<<<n256, b256, 0, stream>>>(excl, partials, 2 * NN, rowptr, cursor);
  fill_csr2<<<edge_blocks2, b256, 0, stream>>>(ei_r0, ei_r1, cursor, csr_src);

  // attention for both relations in one launch
  dst_attention<<<attn_blocks, b256, 0, stream>>>(
      h_dis, Kr0, Vr0, agdi,          // rel0: dst = dis
      h_drug, Kr1, Vr1, agdr,         // rel1: dst = drug
      rowptr, csr_src);

  // update + LayerNorm + ReLU, both node types
  update_ln2<<<2 * gemm_blocks, b256, 0, stream>>>(
      h_drug, agdr, Wut_dr, bu_drug, g_drug, be_drug, h_drug,
      h_dis,  agdi, Wut_di, bu_dis,  g_dis,  be_dis,  h_dis,
      gemm_blocks);
}

// Round 5
// 316.133 us; speedup vs baseline: 20.6653x; 1.1428x over previous
//
#include <hip/hip_runtime.h>
#include <math.h>

#define NN 100000
#define EE 400000
#define DD 128

typedef __attribute__((ext_vector_type(8))) short bf16x8;
typedef __attribute__((ext_vector_type(4))) float f32x4;

__device__ __forceinline__ unsigned short f2bf(float f) {
  unsigned u = __float_as_uint(f);
  u += 0x7FFF + ((u >> 16) & 1);   // round-to-nearest-even
  return (unsigned short)(u >> 16);
}
__device__ __forceinline__ float bf2f(unsigned short u) {
  return __uint_as_float(((unsigned)u) << 16);
}

// ---- one-shot weight prep: 4 transposes + 4 composites + 4 bias composites
__global__ __launch_bounds__(256) void prep_weights(
    const float* __restrict__ Wp_dr, const float* __restrict__ bp_dr,
    const float* __restrict__ Wp_di, const float* __restrict__ bp_di,
    const float* __restrict__ Wu_dr, const float* __restrict__ Wu_di,
    const float* __restrict__ Bk0, const float* __restrict__ Bv0,
    const float* __restrict__ Bk1, const float* __restrict__ Bv1,
    unsigned short* __restrict__ Wpt_dr, unsigned short* __restrict__ Wpt_di,
    unsigned short* __restrict__ Wut_dr, unsigned short* __restrict__ Wut_di,
    unsigned short* __restrict__ Wkt0, float* __restrict__ bk0,
    unsigned short* __restrict__ Wvt0, float* __restrict__ bv0,
    unsigned short* __restrict__ Wkt1, float* __restrict__ bk1,
    unsigned short* __restrict__ Wvt1, float* __restrict__ bv1) {
  const int b = blockIdx.x, t = threadIdx.x;
  if (b < 256) {
    const int id = b * 256 + t;
    const int m = id >> 14, rem = id & 16383, k = rem & 127, c = rem >> 7;
    const float* W = (m == 0) ? Wp_dr : (m == 1) ? Wp_di : (m == 2) ? Wu_dr : Wu_di;
    unsigned short* O = (m == 0) ? Wpt_dr : (m == 1) ? Wpt_di : (m == 2) ? Wut_dr : Wut_di;
    O[c * DD + k] = f2bf(W[(size_t)k * DD + c]);
  } else if (b < 512) {
    const int id = (b - 256) * 256 + t;
    const int m = id >> 14, rem = id & 16383, k = rem & 127, c = rem >> 7;
    const float* A = (m < 2) ? Wp_dr : Wp_di;
    const float* B = (m == 0) ? Bk0 : (m == 1) ? Bv0 : (m == 2) ? Bk1 : Bv1;
    unsigned short* O = (m == 0) ? Wkt0 : (m == 1) ? Wvt0 : (m == 2) ? Wkt1 : Wvt1;
    const float4* a4 = (const float4*)(A + (size_t)k * DD);
    float s = 0.0f;
#pragma unroll 8
    for (int j4 = 0; j4 < 32; ++j4) {
      const float4 av = a4[j4];
      s += av.x * B[(4 * j4 + 0) * DD + c] + av.y * B[(4 * j4 + 1) * DD + c]
         + av.z * B[(4 * j4 + 2) * DD + c] + av.w * B[(4 * j4 + 3) * DD + c];
    }
    O[c * DD + k] = f2bf(s);
  } else {
    const int id = (b - 512) * 256 + t;
    if (id < 512) {
      const int m = id >> 7, c = id & 127;
      const float* bp = (m < 2) ? bp_dr : bp_di;
      const float* B = (m == 0) ? Bk0 : (m == 1) ? Bv0 : (m == 2) ? Bk1 : Bv1;
      float* bo = (m == 0) ? bk0 : (m == 1) ? bv0 : (m == 2) ? bk1 : bv1;
      float s = 0.0f;
#pragma unroll 8
      for (int j = 0; j < DD; ++j) s += bp[j] * B[j * DD + c];
      bo[c] = s;
    }
  }
}

// stage one transposed-bf16 weight (32KB) into LDS with XOR swizzle
#define STAGE_W(SRC)                                                          \
  do {                                                                        \
    __syncthreads();                                                          \
    _Pragma("unroll") for (int i_ = threadIdx.x; i_ < 2048; i_ += 256) {      \
      const int L_ = i_ * 16;                                                 \
      *(float4*)((char*)WL + (L_ ^ (((L_ >> 8) & 7) << 4))) =                 \
          ((const float4*)(SRC))[i_];                                         \
    }                                                                         \
    __syncthreads();                                                          \
  } while (0)

// one wave computes 16 rows x 128 cols: D = A(16x128) @ Wt^T via 8x4 mfma
__device__ __forceinline__ void mfma_tile_store(
    const unsigned short* WL, const bf16x8* a, int lane, int rowbase,
    bool wvalid, const float* __restrict__ bias, float* __restrict__ outf,
    unsigned short* __restrict__ outb) {
  const int r0 = rowbase + (lane >> 4) * 4;
#pragma unroll
  for (int ni = 0; ni < 8; ++ni) {
    const int cl = ni * 16 + (lane & 15);
    f32x4 acc = {0.f, 0.f, 0.f, 0.f};
#pragma unroll
    for (int kk = 0; kk < 4; ++kk) {
      int boff = cl * 256 + kk * 64 + (lane >> 4) * 16;
      boff ^= (cl & 7) << 4;
      const bf16x8 bb = *(const bf16x8*)((const char*)WL + boff);
      acc = __builtin_amdgcn_mfma_f32_16x16x32_bf16(a[kk], bb, acc, 0, 0, 0);
    }
    if (wvalid) {
      const float bv = bias[cl];
      if (outf) {
#pragma unroll
        for (int r = 0; r < 4; ++r)
          outf[(size_t)(r0 + r) * DD + cl] = acc[r] + bv;
      } else {
#pragma unroll
        for (int r = 0; r < 4; ++r)
          outb[(size_t)(r0 + r) * DD + cl] = f2bf(acc[r] + bv);
      }
    }
  }
}

// ---- fused (both types in one launch): h = x@Wp+bp (fp32), K,V (bf16)
__global__ __launch_bounds__(256) void fused_proj(
    const float* __restrict__ x0, const unsigned short* __restrict__ Wpt0,
    const float* __restrict__ bp0, const unsigned short* __restrict__ Wkta,
    const float* __restrict__ bka, const unsigned short* __restrict__ Wvta,
    const float* __restrict__ bva, float* __restrict__ h0,
    unsigned short* __restrict__ K0, unsigned short* __restrict__ V0,
    const float* __restrict__ x1, const unsigned short* __restrict__ Wpt1,
    const float* __restrict__ bp1, const unsigned short* __restrict__ Wktb,
    const float* __restrict__ bkb, const unsigned short* __restrict__ Wvtb,
    const float* __restrict__ bvb, float* __restrict__ h1,
    unsigned short* __restrict__ K1, unsigned short* __restrict__ V1, int half) {
  __shared__ unsigned short WL[DD * DD];
  int bid = blockIdx.x;
  const bool second = bid >= half;
  if (second) bid -= half;
  const float* x = second ? x1 : x0;
  const unsigned short* Wpt = second ? Wpt1 : Wpt0;
  const float* bpv = second ? bp1 : bp0;
  const unsigned short* Wkt = second ? Wktb : Wkta;
  const float* bkv = second ? bkb : bka;
  const unsigned short* Wvt = second ? Wvtb : Wvta;
  const float* bvv = second ? bvb : bva;
  float* h = second ? h1 : h0;
  unsigned short* K = second ? K1 : K0;
  unsigned short* V = second ? V1 : V0;

  const int tid = threadIdx.x, lane = tid & 63, wid = tid >> 6;
  const int rowbase = bid * 64 + wid * 16;
  const bool wvalid = rowbase < NN;
  bf16x8 a[4];
  if (wvalid) {
    const int arow = rowbase + (lane & 15);
    const float* xr = x + (size_t)arow * DD + (lane >> 4) * 8;
#pragma unroll
    for (int kk = 0; kk < 4; ++kk) {
      const float4 f0 = *(const float4*)(xr + kk * 32);
      const float4 f1 = *(const float4*)(xr + kk * 32 + 4);
      a[kk][0] = (short)f2bf(f0.x); a[kk][1] = (short)f2bf(f0.y);
      a[kk][2] = (short)f2bf(f0.z); a[kk][3] = (short)f2bf(f0.w);
      a[kk][4] = (short)f2bf(f1.x); a[kk][5] = (short)f2bf(f1.y);
      a[kk][6] = (short)f2bf(f1.z); a[kk][7] = (short)f2bf(f1.w);
    }
  } else {
#pragma unroll
    for (int kk = 0; kk < 4; ++kk)
#pragma unroll
      for (int j = 0; j < 8; ++j) a[kk][j] = 0;
  }
  STAGE_W(Wpt);
  mfma_tile_store(WL, a, lane, rowbase, wvalid, bpv, h, nullptr);
  STAGE_W(Wkt);
  mfma_tile_store(WL, a, lane, rowbase, wvalid, bkv, nullptr, K);
  STAGE_W(Wvt);
  mfma_tile_store(WL, a, lane, rowbase, wvalid, bvv, nullptr, V);
}

// ---- fused update GEMM (bf16 agg @ Wu) + skip + LayerNorm + ReLU, both types
__global__ __launch_bounds__(256) void update_ln2(
    const float* __restrict__ ha, const unsigned short* __restrict__ agga,
    const unsigned short* __restrict__ Wuta, const float* __restrict__ bua,
    const float* __restrict__ ga, const float* __restrict__ bea,
    float* __restrict__ outa,
    const float* __restrict__ hb, const unsigned short* __restrict__ aggb,
    const unsigned short* __restrict__ Wutb, const float* __restrict__ bub,
    const float* __restrict__ gb, const float* __restrict__ beb,
    float* __restrict__ outb, int half) {
  __shared__ unsigned short WL[DD * DD];
  int bid = blockIdx.x;
  const bool second = bid >= half;
  if (second) bid -= half;
  const float* h = second ? hb : ha;
  const unsigned short* agg = second ? aggb : agga;
  const unsigned short* Wut = second ? Wutb : Wuta;
  const float* bu = second ? bub : bua;
  const float* g = second ? gb : ga;
  const float* be = second ? beb : bea;
  float* out = second ? outb : outa;

  const int tid = threadIdx.x, lane = tid & 63, wid = tid >> 6;
  const int rowbase = bid * 64 + wid * 16;
  const bool wvalid = rowbase < NN;
  bf16x8 a[4];
  if (wvalid) {
    const int arow = rowbase + (lane & 15);
#pragma unroll
    for (int kk = 0; kk < 4; ++kk)
      a[kk] = *(const bf16x8*)(agg + (size_t)arow * DD + kk * 32 + (lane >> 4) * 8);
  } else {
#pragma unroll
    for (int kk = 0; kk < 4; ++kk)
#pragma unroll
      for (int j = 0; j < 8; ++j) a[kk][j] = 0;
  }
  STAGE_W(Wut);
  f32x4 acc[8];
  const int r0 = rowbase + (lane >> 4) * 4;
#pragma unroll
  for (int ni = 0; ni < 8; ++ni) {
    const int cl = ni * 16 + (lane & 15);
    acc[ni] = (f32x4){0.f, 0.f, 0.f, 0.f};
#pragma unroll
    for (int kk = 0; kk < 4; ++kk) {
      int boff = cl * 256 + kk * 64 + (lane >> 4) * 16;
      boff ^= (cl & 7) << 4;
      const bf16x8 bb = *(const bf16x8*)((const char*)WL + boff);
      acc[ni] = __builtin_amdgcn_mfma_f32_16x16x32_bf16(a[kk], bb, acc[ni], 0, 0, 0);
    }
  }
  if (!wvalid) return;
#pragma unroll
  for (int ni = 0; ni < 8; ++ni) {
    const int cl = ni * 16 + (lane & 15);
    const float bv = bu[cl];
#pragma unroll
    for (int r = 0; r < 4; ++r)
      acc[ni][r] += h[(size_t)(r0 + r) * DD + cl] + bv;
  }
  float mean[4], inv[4];
#pragma unroll
  for (int r = 0; r < 4; ++r) {
    float s = 0.f, q = 0.f;
#pragma unroll
    for (int ni = 0; ni < 8; ++ni) {
      const float v = acc[ni][r];
      s += v; q += v * v;
    }
    s += __shfl_xor(s, 1); q += __shfl_xor(q, 1);
    s += __shfl_xor(s, 2); q += __shfl_xor(q, 2);
    s += __shfl_xor(s, 4); q += __shfl_xor(q, 4);
    s += __shfl_xor(s, 8); q += __shfl_xor(q, 8);
    const float mu = s * (1.0f / 128.0f);
    mean[r] = mu;
    inv[r] = rsqrtf(q * (1.0f / 128.0f) - mu * mu + 1e-5f);
  }
#pragma unroll
  for (int ni = 0; ni < 8; ++ni) {
    const int cl = ni * 16 + (lane & 15);
    const float gv = g[cl], bev = be[cl];
#pragma unroll
    for (int r = 0; r < 4; ++r)
      out[(size_t)(r0 + r) * DD + cl] =
          fmaxf((acc[ni][r] - mean[r]) * inv[r] * gv + bev, 0.0f);
  }
}

// ---------------- combined CSR build over both relations (2N nodes, 2E edges)
__global__ __launch_bounds__(256) void count_deg2(const int* __restrict__ ei0,
                                                  const int* __restrict__ ei1,
                                                  int* __restrict__ deg) {
  const int e = blockIdx.x * 256 + threadIdx.x;
  if (e >= 2 * EE) return;
  const int d = (e < EE) ? ei0[EE + e] : (NN + ei1[e]);
  atomicAdd(&deg[d], 1);
}

__global__ __launch_bounds__(256) void scan1(const int* __restrict__ deg,
                                             int* __restrict__ excl,
                                             int* __restrict__ partials, int n) {
  __shared__ int ls[256];
  const int b0 = blockIdx.x * 1024;
  const int t = threadIdx.x;
  int v[4];
  int s = 0;
#pragma unroll
  for (int i = 0; i < 4; ++i) {
    const int idx = b0 + t * 4 + i;
    v[i] = (idx < n) ? deg[idx] : 0;
    s += v[i];
  }
  ls[t] = s;
  __syncthreads();
  for (int off = 1; off < 256; off <<= 1) {
    const int x = (t >= off) ? ls[t - off] : 0;
    __syncthreads();
    ls[t] += x;
    __syncthreads();
  }
  int ex = ls[t] - s;
#pragma unroll
  for (int i = 0; i < 4; ++i) {
    const int idx = b0 + t * 4 + i;
    if (idx < n) excl[idx] = ex;
    ex += v[i];
  }
  if (t == 255) partials[blockIdx.x] = ls[255];
}

__global__ __launch_bounds__(256) void scan2(int* __restrict__ partials, int nb) {
  __shared__ int ls[256];
  const int t = threadIdx.x;
  const int v = (t < nb) ? partials[t] : 0;
  ls[t] = v;
  __syncthreads();
  for (int off = 1; off < 256; off <<= 1) {
    const int x = (t >= off) ? ls[t - off] : 0;
    __syncthreads();
    ls[t] += x;
    __syncthreads();
  }
  if (t < nb) partials[t] = ls[t] - v;
}

__global__ __launch_bounds__(256) void scan3(const int* __restrict__ excl,
                                             const int* __restrict__ partials,
                                             int n, int* __restrict__ rowptr,
                                             int* __restrict__ cursor) {
  const int i = blockIdx.x * 256 + threadIdx.x;
  if (i < n) {
    const int v = excl[i] + partials[i >> 10];
    rowptr[i] = v;
    cursor[i] = v;
  }
  if (i == 0) rowptr[n] = 2 * EE;
}

__global__ __launch_bounds__(256) void fill_csr2(const int* __restrict__ ei0,
                                                 const int* __restrict__ ei1,
                                                 int* __restrict__ cursor,
                                                 int* __restrict__ csr_src) {
  const int e = blockIdx.x * 256 + threadIdx.x;
  if (e >= 2 * EE) return;
  int s, d;
  if (e < EE) { s = ei0[e]; d = ei0[EE + e]; }
  else        { s = ei1[e - EE]; d = NN + ei1[e]; }
  const int p = atomicAdd(&cursor[d], 1);
  csr_src[p] = s;
}

// ---- per-destination attention, 4 edges in flight per wave (16-lane groups).
// No-max softmax (scores ~N(0,1): exp is fp32-safe); two independent sums ->
// zero cross-edge dependency. Lane owns 8 dims (one head per 4-lane cluster).
__global__ __launch_bounds__(256) void dst_attention(
    const float* __restrict__ Hq0, const unsigned short* __restrict__ K0,
    const unsigned short* __restrict__ V0, unsigned short* __restrict__ agg0,
    const float* __restrict__ Hq1, const unsigned short* __restrict__ K1,
    const unsigned short* __restrict__ V1, unsigned short* __restrict__ agg1,
    const int* __restrict__ rowptr, const int* __restrict__ csr_src) {
  const int gw = blockIdx.x * 4 + (threadIdx.x >> 6);
  if (gw >= 2 * NN) return;
  const bool rel1 = gw >= NN;
  const int node = rel1 ? gw - NN : gw;
  const float* Hq = rel1 ? Hq1 : Hq0;
  const unsigned short* K = rel1 ? K1 : K0;
  const unsigned short* V = rel1 ? V1 : V0;
  unsigned short* agg = rel1 ? agg1 : agg0;

  const int lane = threadIdx.x & 63;
  const int sub = lane & 15;   // dim-chunk owner: dims [sub*8, sub*8+8)
  const int grp = lane >> 4;   // edge group 0..3
  const int beg = rowptr[gw], end = rowptr[gw + 1];
  const float4* qp = (const float4*)(Hq + (size_t)node * DD + sub * 8);
  const float4 q0 = qp[0], q1 = qp[1];
  float av[8] = {0.f, 0.f, 0.f, 0.f, 0.f, 0.f, 0.f, 0.f};
  float lsum = 0.0f;
  for (int i = beg + grp; i < end; i += 4) {
    const int sidx = csr_src[i];
    const uint4 kp = *(const uint4*)(K + (size_t)sidx * DD + sub * 8);
    float p;
    p  = q0.x * __uint_as_float(kp.x << 16);
    p += q0.y * __uint_as_float(kp.x & 0xFFFF0000u);
    p += q0.z * __uint_as_float(kp.y << 16);
    p += q0.w * __uint_as_float(kp.y & 0xFFFF0000u);
    p += q1.x * __uint_as_float(kp.z << 16);
    p += q1.y * __uint_as_float(kp.z & 0xFFFF0000u);
    p += q1.z * __uint_as_float(kp.w << 16);
    p += q1.w * __uint_as_float(kp.w & 0xFFFF0000u);
    // head dot: reduce over the 4-lane cluster owning this head's 32 dims
    p += __shfl_xor(p, 1);
    p += __shfl_xor(p, 2);
    const float wgt = __expf(p * 0.17677669529663689f);  // 1/sqrt(32)
    const uint4 vp = *(const uint4*)(V + (size_t)sidx * DD + sub * 8);
    lsum += wgt;
    av[0] += wgt * __uint_as_float(vp.x << 16);
    av[1] += wgt * __uint_as_float(vp.x & 0xFFFF0000u);
    av[2] += wgt * __uint_as_float(vp.y << 16);
    av[3] += wgt * __uint_as_float(vp.y & 0xFFFF0000u);
    av[4] += wgt * __uint_as_float(vp.z << 16);
    av[5] += wgt * __uint_as_float(vp.z & 0xFFFF0000u);
    av[6] += wgt * __uint_as_float(vp.w << 16);
    av[7] += wgt * __uint_as_float(vp.w & 0xFFFF0000u);
  }
  // combine the 4 edge groups (lanes differing in bits 4,5 share sub)
#pragma unroll
  for (int d = 0; d < 8; ++d) {
    av[d] += __shfl_xor(av[d], 16);
    av[d] += __shfl_xor(av[d], 32);
  }
  lsum += __shfl_xor(lsum, 16);
  lsum += __shfl_xor(lsum, 32);
  if (grp == 0) {
    const float invl = (lsum > 0.0f) ? (1.0f / lsum) : 0.0f;
    uint4 o;
    o.x = (unsigned)f2bf(av[0] * invl) | ((unsigned)f2bf(av[1] * invl) << 16);
    o.y = (unsigned)f2bf(av[2] * invl) | ((unsigned)f2bf(av[3] * invl) << 16);
    o.z = (unsigned)f2bf(av[4] * invl) | ((unsigned)f2bf(av[5] * invl) << 16);
    o.w = (unsigned)f2bf(av[6] * invl) | ((unsigned)f2bf(av[7] * invl) << 16);
    *(uint4*)(agg + (size_t)node * DD + sub * 8) = o;
  }
}

extern "C" void kernel_launch(void* const* d_in, const int* in_sizes, int n_in,
                              void* d_out, int out_size, void* d_ws, size_t ws_size,
                              hipStream_t stream) {
  const float* x_drug  = (const float*)d_in[0];
  const float* x_dis   = (const float*)d_in[1];
  const float* Wp_drug = (const float*)d_in[2];
  const float* bp_drug = (const float*)d_in[3];
  const float* Wp_dis  = (const float*)d_in[4];
  const float* bp_dis  = (const float*)d_in[5];
  const float* Wk_r0   = (const float*)d_in[6];
  const float* Wv_r0   = (const float*)d_in[7];
  const float* Wk_r1   = (const float*)d_in[8];
  const float* Wv_r1   = (const float*)d_in[9];
  const float* Wu_drug = (const float*)d_in[10];
  const float* bu_drug = (const float*)d_in[11];
  const float* Wu_dis  = (const float*)d_in[12];
  const float* bu_dis  = (const float*)d_in[13];
  const float* g_drug  = (const float*)d_in[14];
  const float* be_drug = (const float*)d_in[15];
  const float* g_dis   = (const float*)d_in[16];
  const float* be_dis  = (const float*)d_in[17];
  const int* ei_r0     = (const int*)d_in[18];
  const int* ei_r1     = (const int*)d_in[19];

  float* out = (float*)d_out;
  float* h_drug = out;
  float* h_dis  = out + (size_t)NN * DD;

  const size_t ND = (size_t)NN * DD;
  char* w = (char*)d_ws;
  unsigned short* Kr0  = (unsigned short*)w; w += ND * 2;
  unsigned short* Vr0  = (unsigned short*)w; w += ND * 2;
  unsigned short* Kr1  = (unsigned short*)w; w += ND * 2;
  unsigned short* Vr1  = (unsigned short*)w; w += ND * 2;
  unsigned short* agdr = (unsigned short*)w; w += ND * 2;
  unsigned short* agdi = (unsigned short*)w; w += ND * 2;
  unsigned short* Wpt_dr = (unsigned short*)w; w += DD * DD * 2;
  unsigned short* Wpt_di = (unsigned short*)w; w += DD * DD * 2;
  unsigned short* Wut_dr = (unsigned short*)w; w += DD * DD * 2;
  unsigned short* Wut_di = (unsigned short*)w; w += DD * DD * 2;
  unsigned short* Wkt0 = (unsigned short*)w; w += DD * DD * 2;
  unsigned short* Wvt0 = (unsigned short*)w; w += DD * DD * 2;
  unsigned short* Wkt1 = (unsigned short*)w; w += DD * DD * 2;
  unsigned short* Wvt1 = (unsigned short*)w; w += DD * DD * 2;
  float* bk0 = (float*)w; w += DD * 4;
  float* bv0 = (float*)w; w += DD * 4;
  float* bk1 = (float*)w; w += DD * 4;
  float* bv1 = (float*)w; w += DD * 4;
  int* deg      = (int*)w; w += 2 * NN * 4;
  int* excl     = (int*)w; w += 2 * NN * 4;
  int* rowptr   = (int*)w; w += (2 * NN + 1) * 4;
  int* cursor   = (int*)w; w += 2 * NN * 4;
  int* partials = (int*)w; w += 256 * 4;
  int* csr_src  = (int*)w; w += 2 * EE * 4;

  const int gemm_blocks = (NN + 63) / 64;            // 1563
  const int edge_blocks2 = (2 * EE + 255) / 256;     // 3125
  const int nchunks = (2 * NN + 1023) / 1024;        // 196
  const int n256 = (2 * NN + 255) / 256;             // 782
  const int attn_blocks = (2 * NN + 3) / 4;          // 50000
  dim3 b256(256);

  prep_weights<<<514, b256, 0, stream>>>(
      Wp_drug, bp_drug, Wp_dis, bp_dis, Wu_drug, Wu_dis,
      Wk_r0, Wv_r0, Wk_r1, Wv_r1,
      Wpt_dr, Wpt_di, Wut_dr, Wut_di,
      Wkt0, bk0, Wvt0, bv0, Wkt1, bk1, Wvt1, bv1);

  fused_proj<<<2 * gemm_blocks, b256, 0, stream>>>(
      x_drug, Wpt_dr, bp_drug, Wkt0, bk0, Wvt0, bv0, h_drug, Kr0, Vr0,
      x_dis,  Wpt_di, bp_dis,  Wkt1, bk1, Wvt1, bv1, h_dis,  Kr1, Vr1,
      gemm_blocks);

  hipMemsetAsync(deg, 0, 2 * NN * sizeof(int), stream);
  count_deg2<<<edge_blocks2, b256, 0, stream>>>(ei_r0, ei_r1, deg);
  scan1<<<nchunks, b256, 0, stream>>>(deg, excl, partials, 2 * NN);
  scan2<<<1, b256, 0, stream>>>(partials, nchunks);
  scan3<<<n256, b256, 0, stream>>>(excl, partials, 2 * NN, rowptr, cursor);
  fill_csr2<<<edge_blocks2, b256, 0, stream>>>(ei_r0, ei_r1, cursor, csr_src);

  dst_attention<<<attn_blocks, b256, 0, stream>>>(
      h_dis, Kr0, Vr0, agdi,
      h_drug, Kr1, Vr1, agdr,
      rowptr, csr_src);

  update_ln2<<<2 * gemm_blocks, b256, 0, stream>>>(
      h_drug, agdr, Wut_dr, bu_drug, g_drug, be_drug, h_drug,
      h_dis,  agdi, Wut_di, bu_dis,  g_dis,  be_dis,  h_dis,
      gemm_blocks);
}